// Round 3
// baseline (594.701 us; speedup 1.0000x reference)
//
#include <hip/hip_runtime.h>
#include <hip/hip_fp16.h>

// Sparse graph attention (fp32 compute, fp16 gather payloads).
// v5 changes, from round-2 counters:
//  (1) row_kernel was byte/transaction-bound (2x MLP moved NOTHING: same
//      3.6 TB/s, same 148us). Fix: gather k/v/eigs as fp16 (pre-pass
//      conversion, 32MB ws). 640B -> 320B per edge. q, eigs[r], and all
//      accumulation stay fp32; error ~1e-3 << 7.8e-3 tol.
//  (2) build side was unchanged by the p2 LDS fix (297 vs 299) => the
//      ~110us of random 4B stores was in p1's DRAIN (thread-owns-bin =>
//      64 lanes hit 64 bins per instruction). Fix: wave-cooperative drain,
//      one wave per bin, lanes write m<=36 consecutive entries (3 lines
//      instead of 36 scattered transactions).
// Tiers: ws >= need16 -> fp16 path; >= need1 -> fp32 two-pass; >= need2 ->
// direct scatter; else fused atomic path.

#define HD 64
#define ED 32
#define CAP 64          // bucket slots per row
#define RPP 256         // rows per partition
#define PSHIFT 8
#define D1 36           // pass-1 LDS bin depth
#define NB1 256         // pass-1 blocks
#define PCAP 5120       // partition list capacity (mean 4093 at E=1.6M)
#define SPILL_CAP 131072

struct h4 { __half2 a, b; };   // 4 halves, 8B

// ---------------- fp16 conversion pre-pass ----------------
__global__ void cvt16_kernel(const float* __restrict__ src,
                             __half* __restrict__ dst, long long n4) {
    long long t = (long long)blockIdx.x * blockDim.x + threadIdx.x;
    long long stride = (long long)gridDim.x * blockDim.x;
    for (; t < n4; t += stride) {
        float4 f = ((const float4*)src)[t];
        h4 h;
        h.a = __floats2half2_rn(f.x, f.y);
        h.b = __floats2half2_rn(f.z, f.w);
        ((h4*)dst)[t] = h;
    }
}

// ---------------- pass 1: partition binning ----------------
__global__ void p1_bin_kernel(const int* __restrict__ idx, int n_edges,
                              int NP, int chunk,
                              int* __restrict__ part, int* __restrict__ gcur,
                              long long* __restrict__ spill,
                              int* __restrict__ spill_cnt,
                              int* __restrict__ flag) {
    extern __shared__ int sm[];          // [NP] cnt, then [NP*D1] bins
    int* cnt  = sm;
    int* bins = sm + NP;
    int tid = threadIdx.x;

    for (int i = tid; i < NP; i += 256) cnt[i] = 0;
    __syncthreads();

    int e0 = blockIdx.x * chunk;
    int n  = n_edges - e0; if (n > chunk) n = chunk; if (n < 0) n = 0;

    for (int i = tid; i < n; i += 256) {
        int e = e0 + i;
        int r = idx[e];
        int c = idx[n_edges + e];
        int p = r >> PSHIFT;
        int w = ((r & (RPP - 1)) << 17) | c;
        int pos = atomicAdd(&cnt[p], 1);         // LDS atomic
        if (pos < D1) {
            bins[p * D1 + pos] = w;
        } else {                                 // statistical overflow
            int s = atomicAdd(spill_cnt, 1);
            if (s < SPILL_CAP) spill[s] = ((long long)r << 32) | (unsigned)c;
            else *flag = 1;
        }
    }
    __syncthreads();

    // wave-cooperative drain: one wave per bin; lanes 0..m-1 write the
    // bin's m consecutive entries -> ~3 store lines per bin instead of
    // m scattered 4B transactions (this was ~110us of the build).
    int wave = tid >> 6;
    int lane = tid & 63;
    for (int p = wave; p < NP; p += 4) {
        int m = cnt[p]; if (m > D1) m = D1;
        if (m == 0) continue;
        int base = 0;
        if (lane == 0) base = atomicAdd(&gcur[p], m);
        base = __shfl(base, 0, 64);
        if (lane < m) {
            int slot = base + lane;
            int w = bins[p * D1 + lane];
            if (slot < PCAP) {
                part[p * PCAP + slot] = w;
            } else {
                int r = (p << PSHIFT) | (w >> 17);
                int c = w & 0x1FFFF;
                int s = atomicAdd(spill_cnt, 1);
                if (s < SPILL_CAP) spill[s] = ((long long)r << 32) | (unsigned)c;
                else *flag = 1;
            }
        }
    }
}

// ---------------- pass 2: per-half-partition LDS-staged bucket fill ------
__global__ void p2_bucket_kernel(const int* __restrict__ part,
                                 const int* __restrict__ gcur,
                                 int* __restrict__ count,
                                 int* __restrict__ bucket, int n_nodes) {
    __shared__ int cnt[RPP / 2];          // 128 counters
    __shared__ int win[(RPP / 2) * CAP];  // 32KB staged window (uninit ok)
    int tid = threadIdx.x;
    if (tid < RPP / 2) cnt[tid] = 0;
    __syncthreads();

    int p    = blockIdx.x >> 1;
    int half = blockIdx.x & 1;
    int n = gcur[p]; if (n > PCAP) n = PCAP;

    for (int i = tid; i < n; i += 256) {
        int w  = part[p * PCAP + i];
        int rl = w >> 17;                       // 0..255 within partition
        if ((rl >> 7) != half) continue;        // other block's half
        int rh = rl & 127;
        int c  = w & 0x1FFFF;
        int pos = atomicAdd(&cnt[rh], 1);       // LDS atomic
        if (pos < CAP) win[(rh << 6) + pos] = c; // LDS store (fast)
    }
    __syncthreads();

    int r0 = (p << PSHIFT) + (half << 7);       // first row of this half
    int rows = n_nodes - r0;
    if (rows > RPP / 2) rows = RPP / 2;
    if (rows > 0) {
        int nint4 = rows * (CAP / 4);
        int4* dst = (int4*)(bucket + (long long)r0 * CAP);
        const int4* src = (const int4*)win;
        for (int i = tid; i < nint4; i += 256) dst[i] = src[i];
        if (tid < rows) count[r0 + tid] = cnt[tid];
    }
}

// ---------------- spill drain (normally empty) ----------------
__global__ void spill_drain_kernel(const long long* __restrict__ spill,
                                   const int* __restrict__ spill_cnt,
                                   int* __restrict__ count,
                                   int* __restrict__ bucket) {
    int ns = *spill_cnt; if (ns > SPILL_CAP) ns = SPILL_CAP;
    int stride = gridDim.x * blockDim.x;
    for (int t = blockIdx.x * blockDim.x + threadIdx.x; t < ns; t += stride) {
        long long wc = spill[t];
        int r = (int)(wc >> 32);
        int c = (int)(wc & 0xFFFFFFFFLL);
        int pos = atomicAdd(&count[r], 1);
        if (pos < CAP) bucket[(long long)r * CAP + pos] = c;
    }
}

// ---------------- flag-gated repair (all-exit when clean) ----------------
__global__ void repair_zero_kernel(const int* __restrict__ flag,
                                   int* __restrict__ count, int n_nodes) {
    if (*flag == 0) return;
    int t = blockIdx.x * blockDim.x + threadIdx.x;
    if (t < n_nodes) count[t] = 0;
}

__global__ void repair_scatter_kernel(const int* __restrict__ flag,
                                      const int* __restrict__ idx,
                                      int* __restrict__ count,
                                      int* __restrict__ bucket, int n_edges) {
    if (*flag == 0) return;
    int t = blockIdx.x * blockDim.x + threadIdx.x;
    if (t < n_edges) {
        int r = idx[t];
        int c = idx[n_edges + t];
        int p = atomicAdd(&count[r], 1);
        if (p < CAP) bucket[(long long)r * CAP + p] = c;
    }
}

// ---------------- tier-2 build: direct scatter ----------------
__global__ void bucket_scatter_kernel(const int* __restrict__ idx,
                                      int* __restrict__ count,
                                      int* __restrict__ bucket, int n_edges) {
    int t = blockIdx.x * blockDim.x + threadIdx.x;
    if (t < n_edges) {
        int r = idx[t];
        int c = idx[n_edges + t];
        int p = atomicAdd(&count[r], 1);
        if (p < CAP) bucket[(long long)r * CAP + p] = c;
    }
}

// ---------------- row kernel, fp16 gathers ----------------
__global__ void row16_kernel(const float* __restrict__ q,
                             const __half* __restrict__ k16,
                             const __half* __restrict__ v16,
                             const float* __restrict__ eigs,
                             const __half* __restrict__ e16,
                             const float* __restrict__ lambda0,
                             const int* __restrict__ counts,
                             const int* __restrict__ col,
                             const float* __restrict__ kf,
                             const float* __restrict__ vf,
                             const int* __restrict__ idx, int n_edges,
                             float* __restrict__ out, int n_nodes) {
    long long tid = (long long)blockIdx.x * blockDim.x + threadIdx.x;
    int r = (int)(tid >> 6);
    if (r >= n_nodes) return;
    int lane = threadIdx.x & 63;
    int sub = lane & 15;
    int grp = lane >> 4;

    int deg = counts[r];
    const float expL = __expf(lambda0[0]);

    if (deg > CAP) {
        // overflow slow path: rescan edge list with fp32 arrays
        float qs = q[(long long)r * HD + lane] * 0.125f;
        float gs = (lane < ED) ? eigs[(long long)r * ED + lane] * expL : 0.f;
        float accs = 0.f, den = 0.f;
        for (int base = 0; base < n_edges; base += 64) {
            int e = base + lane;
            int rr = (e < n_edges) ? idx[e] : -1;
            int cc = (e < n_edges) ? idx[n_edges + e] : 0;
            unsigned long long mm = __ballot(rr == r);
            while (mm) {
                int b = __ffsll(mm) - 1;
                mm &= mm - 1;
                int c = __shfl(cc, b, 64);
                float kb = kf[(long long)c * HD + lane];
                float gb = (lane < ED) ? eigs[(long long)c * ED + lane] : 0.f;
                float s = qs * kb + gs * gb;
                #pragma unroll
                for (int off = 32; off > 0; off >>= 1) s += __shfl_xor(s, off, 64);
                float e1 = fminf(__expf(s), 5.0f);
                den += e1;
                accs += e1 * vf[(long long)c * HD + lane];
            }
        }
        float inv = (den == 0.f) ? 1.f : __frcp_rn(den);
        out[(long long)r * HD + lane] = accs * inv;
        return;
    }

    long long start = (long long)r * CAP;

    float4 qa = *(const float4*)(q    + (long long)r * HD + sub * 4);
    float2 ga = *(const float2*)(eigs + (long long)r * ED + sub * 2);
    qa.x *= 0.125f; qa.y *= 0.125f; qa.z *= 0.125f; qa.w *= 0.125f;
    ga.x *= expL;   ga.y *= expL;

    float4 acc = make_float4(0.f, 0.f, 0.f, 0.f);
    float den = 0.f;

    for (int base = 0; base < deg; base += 64) {
        int m = deg - base; if (m > 64) m = 64;
        int cl = (lane < m) ? col[start + base + lane] : 0;
        for (int j = 0; j < m; j += 16) {
            int c1 = __shfl(cl, j + grp,      64);
            int c2 = __shfl(cl, j + 4 + grp,  64);
            int c3 = __shfl(cl, j + 8 + grp,  64);
            int c4 = __shfl(cl, j + 12 + grp, 64);
            h4 kb1 = *(const h4*)(k16 + (long long)c1 * HD + sub * 4);
            __half2 gh1 = *(const __half2*)(e16 + (long long)c1 * ED + sub * 2);
            h4 vv1 = *(const h4*)(v16 + (long long)c1 * HD + sub * 4);
            h4 kb2 = *(const h4*)(k16 + (long long)c2 * HD + sub * 4);
            __half2 gh2 = *(const __half2*)(e16 + (long long)c2 * ED + sub * 2);
            h4 vv2 = *(const h4*)(v16 + (long long)c2 * HD + sub * 4);
            h4 kb3 = *(const h4*)(k16 + (long long)c3 * HD + sub * 4);
            __half2 gh3 = *(const __half2*)(e16 + (long long)c3 * ED + sub * 2);
            h4 vv3 = *(const h4*)(v16 + (long long)c3 * HD + sub * 4);
            h4 kb4 = *(const h4*)(k16 + (long long)c4 * HD + sub * 4);
            __half2 gh4 = *(const __half2*)(e16 + (long long)c4 * ED + sub * 2);
            h4 vv4 = *(const h4*)(v16 + (long long)c4 * HD + sub * 4);

            float s1 = qa.x*__low2float(kb1.a) + qa.y*__high2float(kb1.a)
                     + qa.z*__low2float(kb1.b) + qa.w*__high2float(kb1.b)
                     + ga.x*__low2float(gh1)   + ga.y*__high2float(gh1);
            float s2 = qa.x*__low2float(kb2.a) + qa.y*__high2float(kb2.a)
                     + qa.z*__low2float(kb2.b) + qa.w*__high2float(kb2.b)
                     + ga.x*__low2float(gh2)   + ga.y*__high2float(gh2);
            float s3 = qa.x*__low2float(kb3.a) + qa.y*__high2float(kb3.a)
                     + qa.z*__low2float(kb3.b) + qa.w*__high2float(kb3.b)
                     + ga.x*__low2float(gh3)   + ga.y*__high2float(gh3);
            float s4 = qa.x*__low2float(kb4.a) + qa.y*__high2float(kb4.a)
                     + qa.z*__low2float(kb4.b) + qa.w*__high2float(kb4.b)
                     + ga.x*__low2float(gh4)   + ga.y*__high2float(gh4);
            #pragma unroll
            for (int off = 8; off > 0; off >>= 1) {
                s1 += __shfl_xor(s1, off, 64);
                s2 += __shfl_xor(s2, off, 64);
                s3 += __shfl_xor(s3, off, 64);
                s4 += __shfl_xor(s4, off, 64);
            }
            float e1 = fminf(__expf(s1), 5.0f);
            float e2 = fminf(__expf(s2), 5.0f);
            float e3 = fminf(__expf(s3), 5.0f);
            float e4 = fminf(__expf(s4), 5.0f);

            if (j + grp < m) {
                den += e1;
                acc.x += e1 * __low2float(vv1.a); acc.y += e1 * __high2float(vv1.a);
                acc.z += e1 * __low2float(vv1.b); acc.w += e1 * __high2float(vv1.b);
            }
            if (j + 4 + grp < m) {
                den += e2;
                acc.x += e2 * __low2float(vv2.a); acc.y += e2 * __high2float(vv2.a);
                acc.z += e2 * __low2float(vv2.b); acc.w += e2 * __high2float(vv2.b);
            }
            if (j + 8 + grp < m) {
                den += e3;
                acc.x += e3 * __low2float(vv3.a); acc.y += e3 * __high2float(vv3.a);
                acc.z += e3 * __low2float(vv3.b); acc.w += e3 * __high2float(vv3.b);
            }
            if (j + 12 + grp < m) {
                den += e4;
                acc.x += e4 * __low2float(vv4.a); acc.y += e4 * __high2float(vv4.a);
                acc.z += e4 * __low2float(vv4.b); acc.w += e4 * __high2float(vv4.b);
            }
        }
    }

    #pragma unroll
    for (int off = 16; off < 64; off <<= 1) {
        acc.x += __shfl_xor(acc.x, off, 64);
        acc.y += __shfl_xor(acc.y, off, 64);
        acc.z += __shfl_xor(acc.z, off, 64);
        acc.w += __shfl_xor(acc.w, off, 64);
        den   += __shfl_xor(den,   off, 64);
    }

    if (grp == 0) {
        float inv = (den == 0.0f) ? 1.0f : __frcp_rn(den);
        float4 o = make_float4(acc.x * inv, acc.y * inv, acc.z * inv, acc.w * inv);
        *(float4*)(out + (long long)r * HD + sub * 4) = o;
    }
}

// ---------------- row kernel, fp32 (fallback tiers) ----------------
__global__ void row_kernel(const float* __restrict__ q, const float* __restrict__ k,
                           const float* __restrict__ v, const float* __restrict__ eigs,
                           const float* __restrict__ lambda0,
                           const int* __restrict__ counts,
                           const int* __restrict__ col,
                           const int* __restrict__ idx, int n_edges,
                           float* __restrict__ out, int n_nodes) {
    long long tid = (long long)blockIdx.x * blockDim.x + threadIdx.x;
    int r = (int)(tid >> 6);
    if (r >= n_nodes) return;
    int lane = threadIdx.x & 63;
    int sub = lane & 15;
    int grp = lane >> 4;

    int deg = counts[r];
    const float expL = __expf(lambda0[0]);

    if (deg > CAP) {
        float qs = q[(long long)r * HD + lane] * 0.125f;
        float gs = (lane < ED) ? eigs[(long long)r * ED + lane] * expL : 0.f;
        float accs = 0.f, den = 0.f;
        for (int base = 0; base < n_edges; base += 64) {
            int e = base + lane;
            int rr = (e < n_edges) ? idx[e] : -1;
            int cc = (e < n_edges) ? idx[n_edges + e] : 0;
            unsigned long long mm = __ballot(rr == r);
            while (mm) {
                int b = __ffsll(mm) - 1;
                mm &= mm - 1;
                int c = __shfl(cc, b, 64);
                float kb = k[(long long)c * HD + lane];
                float gb = (lane < ED) ? eigs[(long long)c * ED + lane] : 0.f;
                float s = qs * kb + gs * gb;
                #pragma unroll
                for (int off = 32; off > 0; off >>= 1) s += __shfl_xor(s, off, 64);
                float e1 = fminf(__expf(s), 5.0f);
                den += e1;
                accs += e1 * v[(long long)c * HD + lane];
            }
        }
        float inv = (den == 0.f) ? 1.f : __frcp_rn(den);
        out[(long long)r * HD + lane] = accs * inv;
        return;
    }

    long long start = (long long)r * CAP;

    float4 qa = *(const float4*)(q    + (long long)r * HD + sub * 4);
    float2 ga = *(const float2*)(eigs + (long long)r * ED + sub * 2);
    qa.x *= 0.125f; qa.y *= 0.125f; qa.z *= 0.125f; qa.w *= 0.125f;
    ga.x *= expL;   ga.y *= expL;

    float4 acc = make_float4(0.f, 0.f, 0.f, 0.f);
    float den = 0.f;

    for (int base = 0; base < deg; base += 64) {
        int m = deg - base; if (m > 64) m = 64;
        int cl = (lane < m) ? col[start + base + lane] : 0;
        for (int j = 0; j < m; j += 8) {
            int c1 = __shfl(cl, j + grp,     64);
            int c2 = __shfl(cl, j + 4 + grp, 64);
            float4 kb1 = *(const float4*)(k    + (long long)c1 * HD + sub * 4);
            float2 gb1 = *(const float2*)(eigs + (long long)c1 * ED + sub * 2);
            float4 vv1 = *(const float4*)(v    + (long long)c1 * HD + sub * 4);
            float4 kb2 = *(const float4*)(k    + (long long)c2 * HD + sub * 4);
            float2 gb2 = *(const float2*)(eigs + (long long)c2 * ED + sub * 2);
            float4 vv2 = *(const float4*)(v    + (long long)c2 * HD + sub * 4);

            float s1 = qa.x*kb1.x + qa.y*kb1.y + qa.z*kb1.z + qa.w*kb1.w
                     + ga.x*gb1.x + ga.y*gb1.y;
            float s2 = qa.x*kb2.x + qa.y*kb2.y + qa.z*kb2.z + qa.w*kb2.w
                     + ga.x*gb2.x + ga.y*gb2.y;
            #pragma unroll
            for (int off = 8; off > 0; off >>= 1) {
                s1 += __shfl_xor(s1, off, 64);
                s2 += __shfl_xor(s2, off, 64);
            }
            float e1 = fminf(__expf(s1), 5.0f);
            float e2 = fminf(__expf(s2), 5.0f);

            if (j + grp < m) {
                den += e1;
                acc.x += e1 * vv1.x; acc.y += e1 * vv1.y;
                acc.z += e1 * vv1.z; acc.w += e1 * vv1.w;
            }
            if (j + 4 + grp < m) {
                den += e2;
                acc.x += e2 * vv2.x; acc.y += e2 * vv2.y;
                acc.z += e2 * vv2.z; acc.w += e2 * vv2.w;
            }
        }
    }

    #pragma unroll
    for (int off = 16; off < 64; off <<= 1) {
        acc.x += __shfl_xor(acc.x, off, 64);
        acc.y += __shfl_xor(acc.y, off, 64);
        acc.z += __shfl_xor(acc.z, off, 64);
        acc.w += __shfl_xor(acc.w, off, 64);
        den   += __shfl_xor(den,   off, 64);
    }

    if (grp == 0) {
        float inv = (den == 0.0f) ? 1.0f : __frcp_rn(den);
        float4 o = make_float4(acc.x * inv, acc.y * inv, acc.z * inv, acc.w * inv);
        *(float4*)(out + (long long)r * HD + sub * 4) = o;
    }
}

// ---------------- tier-3: fused atomic path ----------------
__global__ void edge_fused_kernel(const float* __restrict__ q,
                                  const float* __restrict__ k,
                                  const float* __restrict__ v,
                                  const float* __restrict__ eigs,
                                  const float* __restrict__ lambda0,
                                  const int* __restrict__ idx,
                                  float* __restrict__ denom,
                                  float* __restrict__ out, int n_edges) {
    long long gid = (long long)blockIdx.x * blockDim.x + threadIdx.x;
    int lane = threadIdx.x & 63;
    int edge = (int)(gid >> 4);
    int sub  = (int)(gid & 15);
    int valid = (edge < n_edges);
    int ec = valid ? edge : (n_edges - 1);
    int i0 = idx[ec];
    int i1 = idx[n_edges + ec];
    const float expL = __expf(lambda0[0]);
    float4 qa = *(const float4*)(q + (long long)i0 * HD + sub * 4);
    float4 kb = *(const float4*)(k + (long long)i1 * HD + sub * 4);
    float c = (qa.x*kb.x + qa.y*kb.y + qa.z*kb.z + qa.w*kb.w) * 0.125f;
    float2 ea = *(const float2*)(eigs + (long long)i0 * ED + sub * 2);
    float2 eb = *(const float2*)(eigs + (long long)i1 * ED + sub * 2);
    c += expL * (ea.x * eb.x + ea.y * eb.y);
    #pragma unroll
    for (int off = 8; off > 0; off >>= 1) c += __shfl_xor(c, off, 64);
    float e = fminf(__expf(c), 5.0f);
    if (valid && sub == 0) atomicAdd(&denom[i0], e);
    #pragma unroll
    for (int j = 0; j < 4; ++j) {
        float ej = __shfl(e,     j * 16, 64);
        int   r  = __shfl(i0,    j * 16, 64);
        int   s  = __shfl(i1,    j * 16, 64);
        int   vj = __shfl(valid, j * 16, 64);
        if (vj) {
            float vv = v[(long long)s * HD + lane];
            atomicAdd(&out[(long long)r * HD + lane], ej * vv);
        }
    }
}

__global__ void normalize_kernel(float* __restrict__ out,
                                 const float* __restrict__ denom, int n_nodes) {
    int t = blockIdx.x * blockDim.x + threadIdx.x;
    int total = n_nodes * (HD / 4);
    if (t >= total) return;
    int row = t >> 4;
    float d = denom[row];
    float inv = (d == 0.0f) ? 1.0f : __frcp_rn(d);
    float4* o4 = (float4*)out;
    float4 x = o4[t];
    x.x *= inv; x.y *= inv; x.z *= inv; x.w *= inv;
    o4[t] = x;
}

extern "C" void kernel_launch(void* const* d_in, const int* in_sizes, int n_in,
                              void* d_out, int out_size, void* d_ws, size_t ws_size,
                              hipStream_t stream) {
    const float* q       = (const float*)d_in[0];
    const float* k       = (const float*)d_in[1];
    const float* v       = (const float*)d_in[2];
    const float* eigs    = (const float*)d_in[3];
    const float* lambda0 = (const float*)d_in[4];
    const int*   idx     = (const int*)d_in[5];   // [2, E], int32

    const int n_edges = in_sizes[5] / 2;
    const int n_nodes = in_sizes[0] / HD;

    const int NP = (n_nodes + RPP - 1) / RPP;
    const int eb = (n_edges + 255) / 256;
    long long rthreads = (long long)n_nodes * 64;
    const int rb = (int)((rthreads + 255) / 256);

    size_t need1 = ((size_t)n_nodes + (size_t)n_nodes * CAP
                    + (size_t)NP * PCAP + NP + 2) * sizeof(int)
                 + (size_t)SPILL_CAP * sizeof(long long);
    size_t need16 = need1 + (size_t)n_nodes * (HD + HD + ED) * sizeof(__half);
    size_t need2 = ((size_t)n_nodes + (size_t)n_nodes * CAP) * sizeof(int);

    if (ws_size >= need16) {
        // -------- tier 1b: two-pass build + fp16 gather row kernel --------
        int* count     = (int*)d_ws;                    // [N]
        int* bucket    = count + n_nodes;               // [N*CAP]
        int* part      = bucket + (size_t)n_nodes * CAP;// [NP*PCAP]
        int* gcur      = part + (size_t)NP * PCAP;      // [NP]
        int* spill_cnt = gcur + NP;                     // [1]
        int* flag      = spill_cnt + 1;                 // [1]
        long long* spill = (long long*)(flag + 1);      // [SPILL_CAP]
        __half* k16 = (__half*)(spill + SPILL_CAP);     // [N*HD]
        __half* v16 = k16 + (size_t)n_nodes * HD;       // [N*HD]
        __half* e16 = v16 + (size_t)n_nodes * HD;       // [N*ED]

        hipMemsetAsync(gcur, 0, (size_t)(NP + 2) * sizeof(int), stream);

        cvt16_kernel<<<1024, 256, 0, stream>>>(k, k16, (long long)n_nodes * HD / 4);
        cvt16_kernel<<<1024, 256, 0, stream>>>(v, v16, (long long)n_nodes * HD / 4);
        cvt16_kernel<<<1024, 256, 0, stream>>>(eigs, e16, (long long)n_nodes * ED / 4);

        int chunk = (n_edges + NB1 - 1) / NB1;
        size_t smbytes = (size_t)NP * (1 + D1) * sizeof(int);
        p1_bin_kernel<<<NB1, 256, smbytes, stream>>>(idx, n_edges, NP, chunk,
                                                     part, gcur, spill,
                                                     spill_cnt, flag);
        p2_bucket_kernel<<<2 * NP, 256, 0, stream>>>(part, gcur, count, bucket,
                                                     n_nodes);
        spill_drain_kernel<<<256, 256, 0, stream>>>(spill, spill_cnt, count,
                                                    bucket);
        repair_zero_kernel<<<(n_nodes + 255) / 256, 256, 0, stream>>>(flag, count,
                                                                      n_nodes);
        repair_scatter_kernel<<<eb, 256, 0, stream>>>(flag, idx, count, bucket,
                                                      n_edges);
        row16_kernel<<<rb, 256, 0, stream>>>(q, k16, v16, eigs, e16, lambda0,
                                             count, bucket, k, v, idx, n_edges,
                                             (float*)d_out, n_nodes);
    } else if (ws_size >= need1) {
        // -------- tier 1: two-pass build + fp32 row kernel --------
        int* count     = (int*)d_ws;
        int* bucket    = count + n_nodes;
        int* part      = bucket + (size_t)n_nodes * CAP;
        int* gcur      = part + (size_t)NP * PCAP;
        int* spill_cnt = gcur + NP;
        int* flag      = spill_cnt + 1;
        long long* spill = (long long*)(flag + 1);

        hipMemsetAsync(gcur, 0, (size_t)(NP + 2) * sizeof(int), stream);

        int chunk = (n_edges + NB1 - 1) / NB1;
        size_t smbytes = (size_t)NP * (1 + D1) * sizeof(int);
        p1_bin_kernel<<<NB1, 256, smbytes, stream>>>(idx, n_edges, NP, chunk,
                                                     part, gcur, spill,
                                                     spill_cnt, flag);
        p2_bucket_kernel<<<2 * NP, 256, 0, stream>>>(part, gcur, count, bucket,
                                                     n_nodes);
        spill_drain_kernel<<<256, 256, 0, stream>>>(spill, spill_cnt, count,
                                                    bucket);
        repair_zero_kernel<<<(n_nodes + 255) / 256, 256, 0, stream>>>(flag, count,
                                                                      n_nodes);
        repair_scatter_kernel<<<eb, 256, 0, stream>>>(flag, idx, count, bucket,
                                                      n_edges);
        row_kernel<<<rb, 256, 0, stream>>>(q, k, v, eigs, lambda0, count, bucket,
                                           idx, n_edges, (float*)d_out, n_nodes);
    } else if (ws_size >= need2) {
        // -------- tier 2: direct scatter --------
        int* count  = (int*)d_ws;
        int* bucket = count + n_nodes;
        hipMemsetAsync(count, 0, (size_t)n_nodes * sizeof(int), stream);
        bucket_scatter_kernel<<<eb, 256, 0, stream>>>(idx, count, bucket, n_edges);
        row_kernel<<<rb, 256, 0, stream>>>(q, k, v, eigs, lambda0, count, bucket,
                                           idx, n_edges, (float*)d_out, n_nodes);
    } else {
        // -------- tier 3: fused atomic path --------
        float* denom = (float*)d_ws;   // [N]
        hipMemsetAsync(denom, 0, (size_t)n_nodes * sizeof(float), stream);
        hipMemsetAsync(d_out, 0, (size_t)out_size * sizeof(float), stream);
        long long threads = (long long)n_edges * 16;
        int grid = (int)((threads + 255) / 256);
        edge_fused_kernel<<<grid, 256, 0, stream>>>(q, k, v, eigs, lambda0, idx,
                                                    denom, (float*)d_out, n_edges);
        int n4 = n_nodes * (HD / 4);
        normalize_kernel<<<(n4 + 255) / 256, 256, 0, stream>>>((float*)d_out,
                                                               denom, n_nodes);
    }
}

// Round 5
// 276.329 us; speedup vs baseline: 2.1521x; 2.1521x over previous
//
#include <hip/hip_runtime.h>
#include <hip/hip_fp16.h>

// Sparse graph attention (fp32 compute, fp16 gather payloads).
// v6 (resubmit — round-4 failure was the MI355X container flake again, same
// signature as round 1; kernel audit found no crash mechanism).
// v6 repairs two v5 bugs identified by round-3 counters:
//  (1) p1 drain serialized on global-atomic latency (310us, VALUBusy 1%,
//      occ 8.6%): one wave handled ~98 bins SEQUENTIALLY, each store
//      dependent on an atomicAdd return (~900cy). Fix: two-phase drain —
//      phase A thread-parallel atomics park bases in LDS (391 concurrent
//      RMWs/block), phase B wave-cooperative coalesced stores with no
//      atomic dependency.
//  (2) fp16 arrays were at ws offset ==4 (mod 8): every 8B h4 gather was
//      misaligned -> split loads + extra line crossings; row16 ran ~230us,
//      WORSE than fp32's 148. Fix: k16/v16/e16 moved to the FRONT of ws
//      (256B-aligned base), ints after, spill rounded up to 8B.
// Tiers: ws >= need16 -> fp16 path; >= need1 -> fp32 two-pass; >= need2 ->
// direct scatter; else fused atomic path.

#define HD 64
#define ED 32
#define CAP 64          // bucket slots per row
#define RPP 256         // rows per partition
#define PSHIFT 8
#define D1 36           // pass-1 LDS bin depth
#define NB1 256         // pass-1 blocks
#define PCAP 5120       // partition list capacity (mean 4093 at E=1.6M)
#define SPILL_CAP 131072

struct h4 { __half2 a, b; };   // 4 halves, 8B

// ---------------- fp16 conversion pre-pass ----------------
__global__ void cvt16_kernel(const float* __restrict__ src,
                             __half* __restrict__ dst, long long n4) {
    long long t = (long long)blockIdx.x * blockDim.x + threadIdx.x;
    long long stride = (long long)gridDim.x * blockDim.x;
    for (; t < n4; t += stride) {
        float4 f = ((const float4*)src)[t];
        h4 h;
        h.a = __floats2half2_rn(f.x, f.y);
        h.b = __floats2half2_rn(f.z, f.w);
        ((h4*)dst)[t] = h;
    }
}

// ---------------- pass 1: partition binning ----------------
__global__ void p1_bin_kernel(const int* __restrict__ idx, int n_edges,
                              int NP, int chunk,
                              int* __restrict__ part, int* __restrict__ gcur,
                              long long* __restrict__ spill,
                              int* __restrict__ spill_cnt,
                              int* __restrict__ flag) {
    extern __shared__ int sm[];          // [NP] cnt, [NP] sbase, [NP*D1] bins
    int* cnt   = sm;
    int* sbase = sm + NP;
    int* bins  = sm + 2 * NP;
    int tid = threadIdx.x;

    for (int i = tid; i < NP; i += 256) cnt[i] = 0;
    __syncthreads();

    int e0 = blockIdx.x * chunk;
    int n  = n_edges - e0; if (n > chunk) n = chunk; if (n < 0) n = 0;

    for (int i = tid; i < n; i += 256) {
        int e = e0 + i;
        int r = idx[e];
        int c = idx[n_edges + e];
        int p = r >> PSHIFT;
        int w = ((r & (RPP - 1)) << 17) | c;
        int pos = atomicAdd(&cnt[p], 1);         // LDS atomic
        if (pos < D1) {
            bins[p * D1 + pos] = w;
        } else {                                 // statistical overflow
            int s = atomicAdd(spill_cnt, 1);
            if (s < SPILL_CAP) spill[s] = ((long long)r << 32) | (unsigned)c;
            else *flag = 1;
        }
    }
    __syncthreads();

    // phase A: thread-parallel slot reservation (391 concurrent global
    // RMWs per block -> atomic latency hidden), bases parked in LDS.
    for (int p = tid; p < NP; p += 256) {
        int m = cnt[p]; if (m > D1) m = D1;
        sbase[p] = (m > 0) ? atomicAdd(&gcur[p], m) : 0;
    }
    __syncthreads();

    // phase B: wave-cooperative coalesced store, no atomic dependency.
    int wave = tid >> 6;
    int lane = tid & 63;
    for (int p = wave; p < NP; p += 4) {
        int m = cnt[p]; if (m > D1) m = D1;
        if (lane < m) {
            int slot = sbase[p] + lane;
            int w = bins[p * D1 + lane];
            if (slot < PCAP) {
                part[p * PCAP + slot] = w;
            } else {
                int r = (p << PSHIFT) | (w >> 17);
                int c = w & 0x1FFFF;
                int s = atomicAdd(spill_cnt, 1);
                if (s < SPILL_CAP) spill[s] = ((long long)r << 32) | (unsigned)c;
                else *flag = 1;
            }
        }
    }
}

// ---------------- pass 2: per-half-partition LDS-staged bucket fill ------
__global__ void p2_bucket_kernel(const int* __restrict__ part,
                                 const int* __restrict__ gcur,
                                 int* __restrict__ count,
                                 int* __restrict__ bucket, int n_nodes) {
    __shared__ int cnt[RPP / 2];          // 128 counters
    __shared__ int win[(RPP / 2) * CAP];  // 32KB staged window (uninit ok)
    int tid = threadIdx.x;
    if (tid < RPP / 2) cnt[tid] = 0;
    __syncthreads();

    int p    = blockIdx.x >> 1;
    int half = blockIdx.x & 1;
    int n = gcur[p]; if (n > PCAP) n = PCAP;

    for (int i = tid; i < n; i += 256) {
        int w  = part[p * PCAP + i];
        int rl = w >> 17;                       // 0..255 within partition
        if ((rl >> 7) != half) continue;        // other block's half
        int rh = rl & 127;
        int c  = w & 0x1FFFF;
        int pos = atomicAdd(&cnt[rh], 1);       // LDS atomic
        if (pos < CAP) win[(rh << 6) + pos] = c; // LDS store (fast)
    }
    __syncthreads();

    int r0 = (p << PSHIFT) + (half << 7);       // first row of this half
    int rows = n_nodes - r0;
    if (rows > RPP / 2) rows = RPP / 2;
    if (rows > 0) {
        int nint4 = rows * (CAP / 4);
        int4* dst = (int4*)(bucket + (long long)r0 * CAP);
        const int4* src = (const int4*)win;
        for (int i = tid; i < nint4; i += 256) dst[i] = src[i];
        if (tid < rows) count[r0 + tid] = cnt[tid];
    }
}

// ---------------- spill drain (normally empty) ----------------
__global__ void spill_drain_kernel(const long long* __restrict__ spill,
                                   const int* __restrict__ spill_cnt,
                                   int* __restrict__ count,
                                   int* __restrict__ bucket) {
    int ns = *spill_cnt; if (ns > SPILL_CAP) ns = SPILL_CAP;
    int stride = gridDim.x * blockDim.x;
    for (int t = blockIdx.x * blockDim.x + threadIdx.x; t < ns; t += stride) {
        long long wc = spill[t];
        int r = (int)(wc >> 32);
        int c = (int)(wc & 0xFFFFFFFFLL);
        int pos = atomicAdd(&count[r], 1);
        if (pos < CAP) bucket[(long long)r * CAP + pos] = c;
    }
}

// ---------------- flag-gated repair (all-exit when clean) ----------------
__global__ void repair_zero_kernel(const int* __restrict__ flag,
                                   int* __restrict__ count, int n_nodes) {
    if (*flag == 0) return;
    int t = blockIdx.x * blockDim.x + threadIdx.x;
    if (t < n_nodes) count[t] = 0;
}

__global__ void repair_scatter_kernel(const int* __restrict__ flag,
                                      const int* __restrict__ idx,
                                      int* __restrict__ count,
                                      int* __restrict__ bucket, int n_edges) {
    if (*flag == 0) return;
    int t = blockIdx.x * blockDim.x + threadIdx.x;
    if (t < n_edges) {
        int r = idx[t];
        int c = idx[n_edges + t];
        int p = atomicAdd(&count[r], 1);
        if (p < CAP) bucket[(long long)r * CAP + p] = c;
    }
}

// ---------------- tier-2 build: direct scatter ----------------
__global__ void bucket_scatter_kernel(const int* __restrict__ idx,
                                      int* __restrict__ count,
                                      int* __restrict__ bucket, int n_edges) {
    int t = blockIdx.x * blockDim.x + threadIdx.x;
    if (t < n_edges) {
        int r = idx[t];
        int c = idx[n_edges + t];
        int p = atomicAdd(&count[r], 1);
        if (p < CAP) bucket[(long long)r * CAP + p] = c;
    }
}

// ---------------- row kernel, fp16 gathers ----------------
__global__ void row16_kernel(const float* __restrict__ q,
                             const __half* __restrict__ k16,
                             const __half* __restrict__ v16,
                             const float* __restrict__ eigs,
                             const __half* __restrict__ e16,
                             const float* __restrict__ lambda0,
                             const int* __restrict__ counts,
                             const int* __restrict__ col,
                             const float* __restrict__ kf,
                             const float* __restrict__ vf,
                             const int* __restrict__ idx, int n_edges,
                             float* __restrict__ out, int n_nodes) {
    long long tid = (long long)blockIdx.x * blockDim.x + threadIdx.x;
    int r = (int)(tid >> 6);
    if (r >= n_nodes) return;
    int lane = threadIdx.x & 63;
    int sub = lane & 15;
    int grp = lane >> 4;

    int deg = counts[r];
    const float expL = __expf(lambda0[0]);

    if (deg > CAP) {
        // overflow slow path: rescan edge list with fp32 arrays
        float qs = q[(long long)r * HD + lane] * 0.125f;
        float gs = (lane < ED) ? eigs[(long long)r * ED + lane] * expL : 0.f;
        float accs = 0.f, den = 0.f;
        for (int base = 0; base < n_edges; base += 64) {
            int e = base + lane;
            int rr = (e < n_edges) ? idx[e] : -1;
            int cc = (e < n_edges) ? idx[n_edges + e] : 0;
            unsigned long long mm = __ballot(rr == r);
            while (mm) {
                int b = __ffsll(mm) - 1;
                mm &= mm - 1;
                int c = __shfl(cc, b, 64);
                float kb = kf[(long long)c * HD + lane];
                float gb = (lane < ED) ? eigs[(long long)c * ED + lane] : 0.f;
                float s = qs * kb + gs * gb;
                #pragma unroll
                for (int off = 32; off > 0; off >>= 1) s += __shfl_xor(s, off, 64);
                float e1 = fminf(__expf(s), 5.0f);
                den += e1;
                accs += e1 * vf[(long long)c * HD + lane];
            }
        }
        float inv = (den == 0.f) ? 1.f : __frcp_rn(den);
        out[(long long)r * HD + lane] = accs * inv;
        return;
    }

    long long start = (long long)r * CAP;

    float4 qa = *(const float4*)(q    + (long long)r * HD + sub * 4);
    float2 ga = *(const float2*)(eigs + (long long)r * ED + sub * 2);
    qa.x *= 0.125f; qa.y *= 0.125f; qa.z *= 0.125f; qa.w *= 0.125f;
    ga.x *= expL;   ga.y *= expL;

    float4 acc = make_float4(0.f, 0.f, 0.f, 0.f);
    float den = 0.f;

    for (int base = 0; base < deg; base += 64) {
        int m = deg - base; if (m > 64) m = 64;
        int cl = (lane < m) ? col[start + base + lane] : 0;
        for (int j = 0; j < m; j += 16) {
            int c1 = __shfl(cl, j + grp,      64);
            int c2 = __shfl(cl, j + 4 + grp,  64);
            int c3 = __shfl(cl, j + 8 + grp,  64);
            int c4 = __shfl(cl, j + 12 + grp, 64);
            h4 kb1 = *(const h4*)(k16 + (long long)c1 * HD + sub * 4);
            __half2 gh1 = *(const __half2*)(e16 + (long long)c1 * ED + sub * 2);
            h4 vv1 = *(const h4*)(v16 + (long long)c1 * HD + sub * 4);
            h4 kb2 = *(const h4*)(k16 + (long long)c2 * HD + sub * 4);
            __half2 gh2 = *(const __half2*)(e16 + (long long)c2 * ED + sub * 2);
            h4 vv2 = *(const h4*)(v16 + (long long)c2 * HD + sub * 4);
            h4 kb3 = *(const h4*)(k16 + (long long)c3 * HD + sub * 4);
            __half2 gh3 = *(const __half2*)(e16 + (long long)c3 * ED + sub * 2);
            h4 vv3 = *(const h4*)(v16 + (long long)c3 * HD + sub * 4);
            h4 kb4 = *(const h4*)(k16 + (long long)c4 * HD + sub * 4);
            __half2 gh4 = *(const __half2*)(e16 + (long long)c4 * ED + sub * 2);
            h4 vv4 = *(const h4*)(v16 + (long long)c4 * HD + sub * 4);

            float s1 = qa.x*__low2float(kb1.a) + qa.y*__high2float(kb1.a)
                     + qa.z*__low2float(kb1.b) + qa.w*__high2float(kb1.b)
                     + ga.x*__low2float(gh1)   + ga.y*__high2float(gh1);
            float s2 = qa.x*__low2float(kb2.a) + qa.y*__high2float(kb2.a)
                     + qa.z*__low2float(kb2.b) + qa.w*__high2float(kb2.b)
                     + ga.x*__low2float(gh2)   + ga.y*__high2float(gh2);
            float s3 = qa.x*__low2float(kb3.a) + qa.y*__high2float(kb3.a)
                     + qa.z*__low2float(kb3.b) + qa.w*__high2float(kb3.b)
                     + ga.x*__low2float(gh3)   + ga.y*__high2float(gh3);
            float s4 = qa.x*__low2float(kb4.a) + qa.y*__high2float(kb4.a)
                     + qa.z*__low2float(kb4.b) + qa.w*__high2float(kb4.b)
                     + ga.x*__low2float(gh4)   + ga.y*__high2float(gh4);
            #pragma unroll
            for (int off = 8; off > 0; off >>= 1) {
                s1 += __shfl_xor(s1, off, 64);
                s2 += __shfl_xor(s2, off, 64);
                s3 += __shfl_xor(s3, off, 64);
                s4 += __shfl_xor(s4, off, 64);
            }
            float e1 = fminf(__expf(s1), 5.0f);
            float e2 = fminf(__expf(s2), 5.0f);
            float e3 = fminf(__expf(s3), 5.0f);
            float e4 = fminf(__expf(s4), 5.0f);

            if (j + grp < m) {
                den += e1;
                acc.x += e1 * __low2float(vv1.a); acc.y += e1 * __high2float(vv1.a);
                acc.z += e1 * __low2float(vv1.b); acc.w += e1 * __high2float(vv1.b);
            }
            if (j + 4 + grp < m) {
                den += e2;
                acc.x += e2 * __low2float(vv2.a); acc.y += e2 * __high2float(vv2.a);
                acc.z += e2 * __low2float(vv2.b); acc.w += e2 * __high2float(vv2.b);
            }
            if (j + 8 + grp < m) {
                den += e3;
                acc.x += e3 * __low2float(vv3.a); acc.y += e3 * __high2float(vv3.a);
                acc.z += e3 * __low2float(vv3.b); acc.w += e3 * __high2float(vv3.b);
            }
            if (j + 12 + grp < m) {
                den += e4;
                acc.x += e4 * __low2float(vv4.a); acc.y += e4 * __high2float(vv4.a);
                acc.z += e4 * __low2float(vv4.b); acc.w += e4 * __high2float(vv4.b);
            }
        }
    }

    #pragma unroll
    for (int off = 16; off < 64; off <<= 1) {
        acc.x += __shfl_xor(acc.x, off, 64);
        acc.y += __shfl_xor(acc.y, off, 64);
        acc.z += __shfl_xor(acc.z, off, 64);
        acc.w += __shfl_xor(acc.w, off, 64);
        den   += __shfl_xor(den,   off, 64);
    }

    if (grp == 0) {
        float inv = (den == 0.0f) ? 1.0f : __frcp_rn(den);
        float4 o = make_float4(acc.x * inv, acc.y * inv, acc.z * inv, acc.w * inv);
        *(float4*)(out + (long long)r * HD + sub * 4) = o;
    }
}

// ---------------- row kernel, fp32 (fallback tiers) ----------------
__global__ void row_kernel(const float* __restrict__ q, const float* __restrict__ k,
                           const float* __restrict__ v, const float* __restrict__ eigs,
                           const float* __restrict__ lambda0,
                           const int* __restrict__ counts,
                           const int* __restrict__ col,
                           const int* __restrict__ idx, int n_edges,
                           float* __restrict__ out, int n_nodes) {
    long long tid = (long long)blockIdx.x * blockDim.x + threadIdx.x;
    int r = (int)(tid >> 6);
    if (r >= n_nodes) return;
    int lane = threadIdx.x & 63;
    int sub = lane & 15;
    int grp = lane >> 4;

    int deg = counts[r];
    const float expL = __expf(lambda0[0]);

    if (deg > CAP) {
        float qs = q[(long long)r * HD + lane] * 0.125f;
        float gs = (lane < ED) ? eigs[(long long)r * ED + lane] * expL : 0.f;
        float accs = 0.f, den = 0.f;
        for (int base = 0; base < n_edges; base += 64) {
            int e = base + lane;
            int rr = (e < n_edges) ? idx[e] : -1;
            int cc = (e < n_edges) ? idx[n_edges + e] : 0;
            unsigned long long mm = __ballot(rr == r);
            while (mm) {
                int b = __ffsll(mm) - 1;
                mm &= mm - 1;
                int c = __shfl(cc, b, 64);
                float kb = k[(long long)c * HD + lane];
                float gb = (lane < ED) ? eigs[(long long)c * ED + lane] : 0.f;
                float s = qs * kb + gs * gb;
                #pragma unroll
                for (int off = 32; off > 0; off >>= 1) s += __shfl_xor(s, off, 64);
                float e1 = fminf(__expf(s), 5.0f);
                den += e1;
                accs += e1 * v[(long long)c * HD + lane];
            }
        }
        float inv = (den == 0.f) ? 1.f : __frcp_rn(den);
        out[(long long)r * HD + lane] = accs * inv;
        return;
    }

    long long start = (long long)r * CAP;

    float4 qa = *(const float4*)(q    + (long long)r * HD + sub * 4);
    float2 ga = *(const float2*)(eigs + (long long)r * ED + sub * 2);
    qa.x *= 0.125f; qa.y *= 0.125f; qa.z *= 0.125f; qa.w *= 0.125f;
    ga.x *= expL;   ga.y *= expL;

    float4 acc = make_float4(0.f, 0.f, 0.f, 0.f);
    float den = 0.f;

    for (int base = 0; base < deg; base += 64) {
        int m = deg - base; if (m > 64) m = 64;
        int cl = (lane < m) ? col[start + base + lane] : 0;
        for (int j = 0; j < m; j += 8) {
            int c1 = __shfl(cl, j + grp,     64);
            int c2 = __shfl(cl, j + 4 + grp, 64);
            float4 kb1 = *(const float4*)(k    + (long long)c1 * HD + sub * 4);
            float2 gb1 = *(const float2*)(eigs + (long long)c1 * ED + sub * 2);
            float4 vv1 = *(const float4*)(v    + (long long)c1 * HD + sub * 4);
            float4 kb2 = *(const float4*)(k    + (long long)c2 * HD + sub * 4);
            float2 gb2 = *(const float2*)(eigs + (long long)c2 * ED + sub * 2);
            float4 vv2 = *(const float4*)(v    + (long long)c2 * HD + sub * 4);

            float s1 = qa.x*kb1.x + qa.y*kb1.y + qa.z*kb1.z + qa.w*kb1.w
                     + ga.x*gb1.x + ga.y*gb1.y;
            float s2 = qa.x*kb2.x + qa.y*kb2.y + qa.z*kb2.z + qa.w*kb2.w
                     + ga.x*gb2.x + ga.y*gb2.y;
            #pragma unroll
            for (int off = 8; off > 0; off >>= 1) {
                s1 += __shfl_xor(s1, off, 64);
                s2 += __shfl_xor(s2, off, 64);
            }
            float e1 = fminf(__expf(s1), 5.0f);
            float e2 = fminf(__expf(s2), 5.0f);

            if (j + grp < m) {
                den += e1;
                acc.x += e1 * vv1.x; acc.y += e1 * vv1.y;
                acc.z += e1 * vv1.z; acc.w += e1 * vv1.w;
            }
            if (j + 4 + grp < m) {
                den += e2;
                acc.x += e2 * vv2.x; acc.y += e2 * vv2.y;
                acc.z += e2 * vv2.z; acc.w += e2 * vv2.w;
            }
        }
    }

    #pragma unroll
    for (int off = 16; off < 64; off <<= 1) {
        acc.x += __shfl_xor(acc.x, off, 64);
        acc.y += __shfl_xor(acc.y, off, 64);
        acc.z += __shfl_xor(acc.z, off, 64);
        acc.w += __shfl_xor(acc.w, off, 64);
        den   += __shfl_xor(den,   off, 64);
    }

    if (grp == 0) {
        float inv = (den == 0.0f) ? 1.0f : __frcp_rn(den);
        float4 o = make_float4(acc.x * inv, acc.y * inv, acc.z * inv, acc.w * inv);
        *(float4*)(out + (long long)r * HD + sub * 4) = o;
    }
}

// ---------------- tier-3: fused atomic path ----------------
__global__ void edge_fused_kernel(const float* __restrict__ q,
                                  const float* __restrict__ k,
                                  const float* __restrict__ v,
                                  const float* __restrict__ eigs,
                                  const float* __restrict__ lambda0,
                                  const int* __restrict__ idx,
                                  float* __restrict__ denom,
                                  float* __restrict__ out, int n_edges) {
    long long gid = (long long)blockIdx.x * blockDim.x + threadIdx.x;
    int lane = threadIdx.x & 63;
    int edge = (int)(gid >> 4);
    int sub  = (int)(gid & 15);
    int valid = (edge < n_edges);
    int ec = valid ? edge : (n_edges - 1);
    int i0 = idx[ec];
    int i1 = idx[n_edges + ec];
    const float expL = __expf(lambda0[0]);
    float4 qa = *(const float4*)(q + (long long)i0 * HD + sub * 4);
    float4 kb = *(const float4*)(k + (long long)i1 * HD + sub * 4);
    float c = (qa.x*kb.x + qa.y*kb.y + qa.z*kb.z + qa.w*kb.w) * 0.125f;
    float2 ea = *(const float2*)(eigs + (long long)i0 * ED + sub * 2);
    float2 eb = *(const float2*)(eigs + (long long)i1 * ED + sub * 2);
    c += expL * (ea.x * eb.x + ea.y * eb.y);
    #pragma unroll
    for (int off = 8; off > 0; off >>= 1) c += __shfl_xor(c, off, 64);
    float e = fminf(__expf(c), 5.0f);
    if (valid && sub == 0) atomicAdd(&denom[i0], e);
    #pragma unroll
    for (int j = 0; j < 4; ++j) {
        float ej = __shfl(e,     j * 16, 64);
        int   r  = __shfl(i0,    j * 16, 64);
        int   s  = __shfl(i1,    j * 16, 64);
        int   vj = __shfl(valid, j * 16, 64);
        if (vj) {
            float vv = v[(long long)s * HD + lane];
            atomicAdd(&out[(long long)r * HD + lane], ej * vv);
        }
    }
}

__global__ void normalize_kernel(float* __restrict__ out,
                                 const float* __restrict__ denom, int n_nodes) {
    int t = blockIdx.x * blockDim.x + threadIdx.x;
    int total = n_nodes * (HD / 4);
    if (t >= total) return;
    int row = t >> 4;
    float d = denom[row];
    float inv = (d == 0.0f) ? 1.0f : __frcp_rn(d);
    float4* o4 = (float4*)out;
    float4 x = o4[t];
    x.x *= inv; x.y *= inv; x.z *= inv; x.w *= inv;
    o4[t] = x;
}

extern "C" void kernel_launch(void* const* d_in, const int* in_sizes, int n_in,
                              void* d_out, int out_size, void* d_ws, size_t ws_size,
                              hipStream_t stream) {
    const float* q       = (const float*)d_in[0];
    const float* k       = (const float*)d_in[1];
    const float* v       = (const float*)d_in[2];
    const float* eigs    = (const float*)d_in[3];
    const float* lambda0 = (const float*)d_in[4];
    const int*   idx     = (const int*)d_in[5];   // [2, E], int32

    const int n_edges = in_sizes[5] / 2;
    const int n_nodes = in_sizes[0] / HD;

    const int NP = (n_nodes + RPP - 1) / RPP;
    const int eb = (n_edges + 255) / 256;
    long long rthreads = (long long)n_nodes * 64;
    const int rb = (int)((rthreads + 255) / 256);

    size_t ints1 = ((size_t)n_nodes + (size_t)n_nodes * CAP
                    + (size_t)NP * PCAP + NP + 2) * sizeof(int);
    size_t need1  = ints1 + 8 + (size_t)SPILL_CAP * sizeof(long long);
    size_t h16    = (size_t)n_nodes * (HD + HD + ED) * sizeof(__half);
    size_t need16 = h16 + need1;
    size_t need2  = ((size_t)n_nodes + (size_t)n_nodes * CAP) * sizeof(int);

    if (ws_size >= need16) {
        // -------- tier 1b: two-pass build + fp16 gather row kernel --------
        // fp16 arrays FIRST (ws base is well-aligned -> 8B-aligned h4 rows)
        char* base = (char*)d_ws;
        __half* k16 = (__half*)base;                    // [N*HD]
        __half* v16 = k16 + (size_t)n_nodes * HD;       // [N*HD]
        __half* e16 = v16 + (size_t)n_nodes * HD;       // [N*ED]
        int* count     = (int*)(e16 + (size_t)n_nodes * ED); // [N]
        int* bucket    = count + n_nodes;               // [N*CAP]
        int* part      = bucket + (size_t)n_nodes * CAP;// [NP*PCAP]
        int* gcur      = part + (size_t)NP * PCAP;      // [NP]
        int* spill_cnt = gcur + NP;                     // [1]
        int* flag      = spill_cnt + 1;                 // [1]
        size_t soff = (size_t)((char*)(flag + 1) - base);
        soff = (soff + 7) & ~(size_t)7;                 // 8B-align spill
        long long* spill = (long long*)(base + soff);   // [SPILL_CAP]

        hipMemsetAsync(gcur, 0, (size_t)(NP + 2) * sizeof(int), stream);

        cvt16_kernel<<<1024, 256, 0, stream>>>(k, k16, (long long)n_nodes * HD / 4);
        cvt16_kernel<<<1024, 256, 0, stream>>>(v, v16, (long long)n_nodes * HD / 4);
        cvt16_kernel<<<1024, 256, 0, stream>>>(eigs, e16, (long long)n_nodes * ED / 4);

        int chunk = (n_edges + NB1 - 1) / NB1;
        size_t smbytes = (size_t)NP * (2 + D1) * sizeof(int);
        p1_bin_kernel<<<NB1, 256, smbytes, stream>>>(idx, n_edges, NP, chunk,
                                                     part, gcur, spill,
                                                     spill_cnt, flag);
        p2_bucket_kernel<<<2 * NP, 256, 0, stream>>>(part, gcur, count, bucket,
                                                     n_nodes);
        spill_drain_kernel<<<256, 256, 0, stream>>>(spill, spill_cnt, count,
                                                    bucket);
        repair_zero_kernel<<<(n_nodes + 255) / 256, 256, 0, stream>>>(flag, count,
                                                                      n_nodes);
        repair_scatter_kernel<<<eb, 256, 0, stream>>>(flag, idx, count, bucket,
                                                      n_edges);
        row16_kernel<<<rb, 256, 0, stream>>>(q, k16, v16, eigs, e16, lambda0,
                                             count, bucket, k, v, idx, n_edges,
                                             (float*)d_out, n_nodes);
    } else if (ws_size >= need1) {
        // -------- tier 1: two-pass build + fp32 row kernel --------
        char* base = (char*)d_ws;
        int* count     = (int*)base;
        int* bucket    = count + n_nodes;
        int* part      = bucket + (size_t)n_nodes * CAP;
        int* gcur      = part + (size_t)NP * PCAP;
        int* spill_cnt = gcur + NP;
        int* flag      = spill_cnt + 1;
        size_t soff = (size_t)((char*)(flag + 1) - base);
        soff = (soff + 7) & ~(size_t)7;
        long long* spill = (long long*)(base + soff);

        hipMemsetAsync(gcur, 0, (size_t)(NP + 2) * sizeof(int), stream);

        int chunk = (n_edges + NB1 - 1) / NB1;
        size_t smbytes = (size_t)NP * (2 + D1) * sizeof(int);
        p1_bin_kernel<<<NB1, 256, smbytes, stream>>>(idx, n_edges, NP, chunk,
                                                     part, gcur, spill,
                                                     spill_cnt, flag);
        p2_bucket_kernel<<<2 * NP, 256, 0, stream>>>(part, gcur, count, bucket,
                                                     n_nodes);
        spill_drain_kernel<<<256, 256, 0, stream>>>(spill, spill_cnt, count,
                                                    bucket);
        repair_zero_kernel<<<(n_nodes + 255) / 256, 256, 0, stream>>>(flag, count,
                                                                      n_nodes);
        repair_scatter_kernel<<<eb, 256, 0, stream>>>(flag, idx, count, bucket,
                                                      n_edges);
        row_kernel<<<rb, 256, 0, stream>>>(q, k, v, eigs, lambda0, count, bucket,
                                           idx, n_edges, (float*)d_out, n_nodes);
    } else if (ws_size >= need2) {
        // -------- tier 2: direct scatter --------
        int* count  = (int*)d_ws;
        int* bucket = count + n_nodes;
        hipMemsetAsync(count, 0, (size_t)n_nodes * sizeof(int), stream);
        bucket_scatter_kernel<<<eb, 256, 0, stream>>>(idx, count, bucket, n_edges);
        row_kernel<<<rb, 256, 0, stream>>>(q, k, v, eigs, lambda0, count, bucket,
                                           idx, n_edges, (float*)d_out, n_nodes);
    } else {
        // -------- tier 3: fused atomic path --------
        float* denom = (float*)d_ws;   // [N]
        hipMemsetAsync(denom, 0, (size_t)n_nodes * sizeof(float), stream);
        hipMemsetAsync(d_out, 0, (size_t)out_size * sizeof(float), stream);
        long long threads = (long long)n_edges * 16;
        int grid = (int)((threads + 255) / 256);
        edge_fused_kernel<<<grid, 256, 0, stream>>>(q, k, v, eigs, lambda0, idx,
                                                    denom, (float*)d_out, n_edges);
        int n4 = n_nodes * (HD / 4);
        normalize_kernel<<<(n4 + 255) / 256, 256, 0, stream>>>((float*)d_out,
                                                               denom, n_nodes);
    }
}

// Round 6
// 263.406 us; speedup vs baseline: 2.2577x; 1.0491x over previous
//
#include <hip/hip_runtime.h>
#include <hip/hip_fp16.h>

// Sparse graph attention (fp32 compute, fp16 gather payloads).
// v7: build-side consolidation from round-5 counters (row16=87us as
// predicted; build+gaps=189us over 9 dispatches, each <87us):
//  (1) p1 occupancy 4x: NB1 256->1024 blocks, D1 36->16 (lambda~4/bin,
//      P(overflow)~1e-6 -> spill path absorbs). LDS 59.4->28.2KB.
//      Old launch was 1 block/CU = 2 waves/SIMD -> no latency hiding for
//      the idx-load + LDS-atomic chains. Drain: 16-lane-per-bin bursts.
//  (2) cvt16 x3 fused into p1's tail (no sync needed; overlaps drain).
//  (3) spill_drain + repair_zero merged (flag branch). 10 -> 6 dispatches.
// row16 unchanged (87us, matches model) for clean attribution.

#define HD 64
#define ED 32
#define CAP 64          // bucket slots per row
#define RPP 256         // rows per partition
#define PSHIFT 8
#define D1 16           // pass-1 LDS bin depth (lambda ~4 at NB1=1024)
#define NB1 1024        // pass-1 blocks (4 blocks/CU)
#define PCAP 5120       // partition list capacity (mean 4093 at E=1.6M)
#define SPILL_CAP 131072

struct h4 { __half2 a, b; };   // 4 halves, 8B

// ---------------- pass 1: partition binning (+fused fp16 cvt tail) ------
__global__ void p1_bin_kernel(const int* __restrict__ idx, int n_edges,
                              int NP, int chunk,
                              int* __restrict__ part, int* __restrict__ gcur,
                              long long* __restrict__ spill,
                              int* __restrict__ spill_cnt,
                              int* __restrict__ flag,
                              const float* __restrict__ kf,
                              const float* __restrict__ vf,
                              const float* __restrict__ ef,
                              __half* __restrict__ k16,
                              __half* __restrict__ v16,
                              __half* __restrict__ e16,
                              long long nk4, long long ne4) {
    extern __shared__ int sm[];          // [NP] cnt, [NP] sbase, [NP*D1] bins
    int* cnt   = sm;
    int* sbase = sm + NP;
    int* bins  = sm + 2 * NP;
    int tid = threadIdx.x;

    for (int i = tid; i < NP; i += 256) cnt[i] = 0;
    __syncthreads();

    int e0 = blockIdx.x * chunk;
    int n  = n_edges - e0; if (n > chunk) n = chunk; if (n < 0) n = 0;

    for (int i = tid; i < n; i += 256) {
        int e = e0 + i;
        int r = idx[e];
        int c = idx[n_edges + e];
        int p = r >> PSHIFT;
        int w = ((r & (RPP - 1)) << 17) | c;
        int pos = atomicAdd(&cnt[p], 1);         // LDS atomic
        if (pos < D1) {
            bins[p * D1 + pos] = w;
        } else {                                 // statistical overflow
            int s = atomicAdd(spill_cnt, 1);
            if (s < SPILL_CAP) spill[s] = ((long long)r << 32) | (unsigned)c;
            else *flag = 1;
        }
    }
    __syncthreads();

    // phase A: thread-parallel slot reservation (concurrent global RMWs),
    // bases parked in LDS.
    for (int p = tid; p < NP; p += 256) {
        int m = cnt[p]; if (m > D1) m = D1;
        sbase[p] = (m > 0) ? atomicAdd(&gcur[p], m) : 0;
    }
    __syncthreads();

    // phase B: 16-lane-per-bin coalesced bursts, 4 bins per wave per iter,
    // no atomic dependency.
    int wave = tid >> 6;
    int lane = tid & 63;
    int sg = lane >> 4;      // subgroup 0..3 (bin select)
    int sl = lane & 15;      // slot 0..15
    for (int p0 = wave * 4; p0 < NP; p0 += 16) {
        int p = p0 + sg;
        if (p < NP) {
            int m = cnt[p]; if (m > D1) m = D1;
            if (sl < m) {
                int slot = sbase[p] + sl;
                int w = bins[p * D1 + sl];
                if (slot < PCAP) {
                    part[p * PCAP + slot] = w;
                } else {
                    int r = (p << PSHIFT) | (w >> 17);
                    int c = w & 0x1FFFF;
                    int s = atomicAdd(spill_cnt, 1);
                    if (s < SPILL_CAP) spill[s] = ((long long)r << 32) | (unsigned)c;
                    else *flag = 1;
                }
            }
        }
    }

    // fused fp16 conversion tail (independent streaming; no sync needed —
    // row16 is a later dispatch). Skipped when k16==nullptr (fp32 tier).
    if (k16 != nullptr) {
        long long gt = (long long)blockIdx.x * 256 + tid;
        long long gs = (long long)gridDim.x * 256;
        for (long long t = gt; t < nk4; t += gs) {
            float4 f = ((const float4*)kf)[t];
            h4 h;
            h.a = __floats2half2_rn(f.x, f.y);
            h.b = __floats2half2_rn(f.z, f.w);
            ((h4*)k16)[t] = h;
        }
        for (long long t = gt; t < nk4; t += gs) {
            float4 f = ((const float4*)vf)[t];
            h4 h;
            h.a = __floats2half2_rn(f.x, f.y);
            h.b = __floats2half2_rn(f.z, f.w);
            ((h4*)v16)[t] = h;
        }
        for (long long t = gt; t < ne4; t += gs) {
            float4 f = ((const float4*)ef)[t];
            h4 h;
            h.a = __floats2half2_rn(f.x, f.y);
            h.b = __floats2half2_rn(f.z, f.w);
            ((h4*)e16)[t] = h;
        }
    }
}

// ---------------- pass 2: per-half-partition LDS-staged bucket fill ------
__global__ void p2_bucket_kernel(const int* __restrict__ part,
                                 const int* __restrict__ gcur,
                                 int* __restrict__ count,
                                 int* __restrict__ bucket, int n_nodes) {
    __shared__ int cnt[RPP / 2];          // 128 counters
    __shared__ int win[(RPP / 2) * CAP];  // 32KB staged window (uninit ok)
    int tid = threadIdx.x;
    if (tid < RPP / 2) cnt[tid] = 0;
    __syncthreads();

    int p    = blockIdx.x >> 1;
    int half = blockIdx.x & 1;
    int n = gcur[p]; if (n > PCAP) n = PCAP;

    for (int i = tid; i < n; i += 256) {
        int w  = part[p * PCAP + i];
        int rl = w >> 17;                       // 0..255 within partition
        if ((rl >> 7) != half) continue;        // other block's half
        int rh = rl & 127;
        int c  = w & 0x1FFFF;
        int pos = atomicAdd(&cnt[rh], 1);       // LDS atomic
        if (pos < CAP) win[(rh << 6) + pos] = c; // LDS store (fast)
    }
    __syncthreads();

    int r0 = (p << PSHIFT) + (half << 7);       // first row of this half
    int rows = n_nodes - r0;
    if (rows > RPP / 2) rows = RPP / 2;
    if (rows > 0) {
        int nint4 = rows * (CAP / 4);
        int4* dst = (int4*)(bucket + (long long)r0 * CAP);
        const int4* src = (const int4*)win;
        for (int i = tid; i < nint4; i += 256) dst[i] = src[i];
        if (tid < rows) count[r0 + tid] = cnt[tid];
    }
}

// ---------------- spill drain OR count-zero (flag branch) ----------------
__global__ void spill_or_zero_kernel(const long long* __restrict__ spill,
                                     const int* __restrict__ spill_cnt,
                                     const int* __restrict__ flag,
                                     int* __restrict__ count,
                                     int* __restrict__ bucket, int n_nodes) {
    int stride = gridDim.x * blockDim.x;
    int t0 = blockIdx.x * blockDim.x + threadIdx.x;
    if (*flag) {
        // overflow catastrophe: zero counts; repair_scatter rebuilds.
        for (int t = t0; t < n_nodes; t += stride) count[t] = 0;
        return;
    }
    int ns = *spill_cnt; if (ns > SPILL_CAP) ns = SPILL_CAP;
    for (int t = t0; t < ns; t += stride) {
        long long wc = spill[t];
        int r = (int)(wc >> 32);
        int c = (int)(wc & 0xFFFFFFFFLL);
        int pos = atomicAdd(&count[r], 1);
        if (pos < CAP) bucket[(long long)r * CAP + pos] = c;
    }
}

__global__ void repair_scatter_kernel(const int* __restrict__ flag,
                                      const int* __restrict__ idx,
                                      int* __restrict__ count,
                                      int* __restrict__ bucket, int n_edges) {
    if (*flag == 0) return;
    int t = blockIdx.x * blockDim.x + threadIdx.x;
    if (t < n_edges) {
        int r = idx[t];
        int c = idx[n_edges + t];
        int p = atomicAdd(&count[r], 1);
        if (p < CAP) bucket[(long long)r * CAP + p] = c;
    }
}

// ---------------- tier-2 build: direct scatter ----------------
__global__ void bucket_scatter_kernel(const int* __restrict__ idx,
                                      int* __restrict__ count,
                                      int* __restrict__ bucket, int n_edges) {
    int t = blockIdx.x * blockDim.x + threadIdx.x;
    if (t < n_edges) {
        int r = idx[t];
        int c = idx[n_edges + t];
        int p = atomicAdd(&count[r], 1);
        if (p < CAP) bucket[(long long)r * CAP + p] = c;
    }
}

// ---------------- row kernel, fp16 gathers ----------------
__global__ void row16_kernel(const float* __restrict__ q,
                             const __half* __restrict__ k16,
                             const __half* __restrict__ v16,
                             const float* __restrict__ eigs,
                             const __half* __restrict__ e16,
                             const float* __restrict__ lambda0,
                             const int* __restrict__ counts,
                             const int* __restrict__ col,
                             const float* __restrict__ kf,
                             const float* __restrict__ vf,
                             const int* __restrict__ idx, int n_edges,
                             float* __restrict__ out, int n_nodes) {
    long long tid = (long long)blockIdx.x * blockDim.x + threadIdx.x;
    int r = (int)(tid >> 6);
    if (r >= n_nodes) return;
    int lane = threadIdx.x & 63;
    int sub = lane & 15;
    int grp = lane >> 4;

    int deg = counts[r];
    const float expL = __expf(lambda0[0]);

    if (deg > CAP) {
        // overflow slow path: rescan edge list with fp32 arrays
        float qs = q[(long long)r * HD + lane] * 0.125f;
        float gs = (lane < ED) ? eigs[(long long)r * ED + lane] * expL : 0.f;
        float accs = 0.f, den = 0.f;
        for (int base = 0; base < n_edges; base += 64) {
            int e = base + lane;
            int rr = (e < n_edges) ? idx[e] : -1;
            int cc = (e < n_edges) ? idx[n_edges + e] : 0;
            unsigned long long mm = __ballot(rr == r);
            while (mm) {
                int b = __ffsll(mm) - 1;
                mm &= mm - 1;
                int c = __shfl(cc, b, 64);
                float kb = kf[(long long)c * HD + lane];
                float gb = (lane < ED) ? eigs[(long long)c * ED + lane] : 0.f;
                float s = qs * kb + gs * gb;
                #pragma unroll
                for (int off = 32; off > 0; off >>= 1) s += __shfl_xor(s, off, 64);
                float e1 = fminf(__expf(s), 5.0f);
                den += e1;
                accs += e1 * vf[(long long)c * HD + lane];
            }
        }
        float inv = (den == 0.f) ? 1.f : __frcp_rn(den);
        out[(long long)r * HD + lane] = accs * inv;
        return;
    }

    long long start = (long long)r * CAP;

    float4 qa = *(const float4*)(q    + (long long)r * HD + sub * 4);
    float2 ga = *(const float2*)(eigs + (long long)r * ED + sub * 2);
    qa.x *= 0.125f; qa.y *= 0.125f; qa.z *= 0.125f; qa.w *= 0.125f;
    ga.x *= expL;   ga.y *= expL;

    float4 acc = make_float4(0.f, 0.f, 0.f, 0.f);
    float den = 0.f;

    for (int base = 0; base < deg; base += 64) {
        int m = deg - base; if (m > 64) m = 64;
        int cl = (lane < m) ? col[start + base + lane] : 0;
        for (int j = 0; j < m; j += 16) {
            int c1 = __shfl(cl, j + grp,      64);
            int c2 = __shfl(cl, j + 4 + grp,  64);
            int c3 = __shfl(cl, j + 8 + grp,  64);
            int c4 = __shfl(cl, j + 12 + grp, 64);
            h4 kb1 = *(const h4*)(k16 + (long long)c1 * HD + sub * 4);
            __half2 gh1 = *(const __half2*)(e16 + (long long)c1 * ED + sub * 2);
            h4 vv1 = *(const h4*)(v16 + (long long)c1 * HD + sub * 4);
            h4 kb2 = *(const h4*)(k16 + (long long)c2 * HD + sub * 4);
            __half2 gh2 = *(const __half2*)(e16 + (long long)c2 * ED + sub * 2);
            h4 vv2 = *(const h4*)(v16 + (long long)c2 * HD + sub * 4);
            h4 kb3 = *(const h4*)(k16 + (long long)c3 * HD + sub * 4);
            __half2 gh3 = *(const __half2*)(e16 + (long long)c3 * ED + sub * 2);
            h4 vv3 = *(const h4*)(v16 + (long long)c3 * HD + sub * 4);
            h4 kb4 = *(const h4*)(k16 + (long long)c4 * HD + sub * 4);
            __half2 gh4 = *(const __half2*)(e16 + (long long)c4 * ED + sub * 2);
            h4 vv4 = *(const h4*)(v16 + (long long)c4 * HD + sub * 4);

            float s1 = qa.x*__low2float(kb1.a) + qa.y*__high2float(kb1.a)
                     + qa.z*__low2float(kb1.b) + qa.w*__high2float(kb1.b)
                     + ga.x*__low2float(gh1)   + ga.y*__high2float(gh1);
            float s2 = qa.x*__low2float(kb2.a) + qa.y*__high2float(kb2.a)
                     + qa.z*__low2float(kb2.b) + qa.w*__high2float(kb2.b)
                     + ga.x*__low2float(gh2)   + ga.y*__high2float(gh2);
            float s3 = qa.x*__low2float(kb3.a) + qa.y*__high2float(kb3.a)
                     + qa.z*__low2float(kb3.b) + qa.w*__high2float(kb3.b)
                     + ga.x*__low2float(gh3)   + ga.y*__high2float(gh3);
            float s4 = qa.x*__low2float(kb4.a) + qa.y*__high2float(kb4.a)
                     + qa.z*__low2float(kb4.b) + qa.w*__high2float(kb4.b)
                     + ga.x*__low2float(gh4)   + ga.y*__high2float(gh4);
            #pragma unroll
            for (int off = 8; off > 0; off >>= 1) {
                s1 += __shfl_xor(s1, off, 64);
                s2 += __shfl_xor(s2, off, 64);
                s3 += __shfl_xor(s3, off, 64);
                s4 += __shfl_xor(s4, off, 64);
            }
            float e1 = fminf(__expf(s1), 5.0f);
            float e2 = fminf(__expf(s2), 5.0f);
            float e3 = fminf(__expf(s3), 5.0f);
            float e4 = fminf(__expf(s4), 5.0f);

            if (j + grp < m) {
                den += e1;
                acc.x += e1 * __low2float(vv1.a); acc.y += e1 * __high2float(vv1.a);
                acc.z += e1 * __low2float(vv1.b); acc.w += e1 * __high2float(vv1.b);
            }
            if (j + 4 + grp < m) {
                den += e2;
                acc.x += e2 * __low2float(vv2.a); acc.y += e2 * __high2float(vv2.a);
                acc.z += e2 * __low2float(vv2.b); acc.w += e2 * __high2float(vv2.b);
            }
            if (j + 8 + grp < m) {
                den += e3;
                acc.x += e3 * __low2float(vv3.a); acc.y += e3 * __high2float(vv3.a);
                acc.z += e3 * __low2float(vv3.b); acc.w += e3 * __high2float(vv3.b);
            }
            if (j + 12 + grp < m) {
                den += e4;
                acc.x += e4 * __low2float(vv4.a); acc.y += e4 * __high2float(vv4.a);
                acc.z += e4 * __low2float(vv4.b); acc.w += e4 * __high2float(vv4.b);
            }
        }
    }

    #pragma unroll
    for (int off = 16; off < 64; off <<= 1) {
        acc.x += __shfl_xor(acc.x, off, 64);
        acc.y += __shfl_xor(acc.y, off, 64);
        acc.z += __shfl_xor(acc.z, off, 64);
        acc.w += __shfl_xor(acc.w, off, 64);
        den   += __shfl_xor(den,   off, 64);
    }

    if (grp == 0) {
        float inv = (den == 0.0f) ? 1.0f : __frcp_rn(den);
        float4 o = make_float4(acc.x * inv, acc.y * inv, acc.z * inv, acc.w * inv);
        *(float4*)(out + (long long)r * HD + sub * 4) = o;
    }
}

// ---------------- row kernel, fp32 (fallback tiers) ----------------
__global__ void row_kernel(const float* __restrict__ q, const float* __restrict__ k,
                           const float* __restrict__ v, const float* __restrict__ eigs,
                           const float* __restrict__ lambda0,
                           const int* __restrict__ counts,
                           const int* __restrict__ col,
                           const int* __restrict__ idx, int n_edges,
                           float* __restrict__ out, int n_nodes) {
    long long tid = (long long)blockIdx.x * blockDim.x + threadIdx.x;
    int r = (int)(tid >> 6);
    if (r >= n_nodes) return;
    int lane = threadIdx.x & 63;
    int sub = lane & 15;
    int grp = lane >> 4;

    int deg = counts[r];
    const float expL = __expf(lambda0[0]);

    if (deg > CAP) {
        float qs = q[(long long)r * HD + lane] * 0.125f;
        float gs = (lane < ED) ? eigs[(long long)r * ED + lane] * expL : 0.f;
        float accs = 0.f, den = 0.f;
        for (int base = 0; base < n_edges; base += 64) {
            int e = base + lane;
            int rr = (e < n_edges) ? idx[e] : -1;
            int cc = (e < n_edges) ? idx[n_edges + e] : 0;
            unsigned long long mm = __ballot(rr == r);
            while (mm) {
                int b = __ffsll(mm) - 1;
                mm &= mm - 1;
                int c = __shfl(cc, b, 64);
                float kb = k[(long long)c * HD + lane];
                float gb = (lane < ED) ? eigs[(long long)c * ED + lane] : 0.f;
                float s = qs * kb + gs * gb;
                #pragma unroll
                for (int off = 32; off > 0; off >>= 1) s += __shfl_xor(s, off, 64);
                float e1 = fminf(__expf(s), 5.0f);
                den += e1;
                accs += e1 * v[(long long)c * HD + lane];
            }
        }
        float inv = (den == 0.f) ? 1.f : __frcp_rn(den);
        out[(long long)r * HD + lane] = accs * inv;
        return;
    }

    long long start = (long long)r * CAP;

    float4 qa = *(const float4*)(q    + (long long)r * HD + sub * 4);
    float2 ga = *(const float2*)(eigs + (long long)r * ED + sub * 2);
    qa.x *= 0.125f; qa.y *= 0.125f; qa.z *= 0.125f; qa.w *= 0.125f;
    ga.x *= expL;   ga.y *= expL;

    float4 acc = make_float4(0.f, 0.f, 0.f, 0.f);
    float den = 0.f;

    for (int base = 0; base < deg; base += 64) {
        int m = deg - base; if (m > 64) m = 64;
        int cl = (lane < m) ? col[start + base + lane] : 0;
        for (int j = 0; j < m; j += 8) {
            int c1 = __shfl(cl, j + grp,     64);
            int c2 = __shfl(cl, j + 4 + grp, 64);
            float4 kb1 = *(const float4*)(k    + (long long)c1 * HD + sub * 4);
            float2 gb1 = *(const float2*)(eigs + (long long)c1 * ED + sub * 2);
            float4 vv1 = *(const float4*)(v    + (long long)c1 * HD + sub * 4);
            float4 kb2 = *(const float4*)(k    + (long long)c2 * HD + sub * 4);
            float2 gb2 = *(const float2*)(eigs + (long long)c2 * ED + sub * 2);
            float4 vv2 = *(const float4*)(v    + (long long)c2 * HD + sub * 4);

            float s1 = qa.x*kb1.x + qa.y*kb1.y + qa.z*kb1.z + qa.w*kb1.w
                     + ga.x*gb1.x + ga.y*gb1.y;
            float s2 = qa.x*kb2.x + qa.y*kb2.y + qa.z*kb2.z + qa.w*kb2.w
                     + ga.x*gb2.x + ga.y*gb2.y;
            #pragma unroll
            for (int off = 8; off > 0; off >>= 1) {
                s1 += __shfl_xor(s1, off, 64);
                s2 += __shfl_xor(s2, off, 64);
            }
            float e1 = fminf(__expf(s1), 5.0f);
            float e2 = fminf(__expf(s2), 5.0f);

            if (j + grp < m) {
                den += e1;
                acc.x += e1 * vv1.x; acc.y += e1 * vv1.y;
                acc.z += e1 * vv1.z; acc.w += e1 * vv1.w;
            }
            if (j + 4 + grp < m) {
                den += e2;
                acc.x += e2 * vv2.x; acc.y += e2 * vv2.y;
                acc.z += e2 * vv2.z; acc.w += e2 * vv2.w;
            }
        }
    }

    #pragma unroll
    for (int off = 16; off < 64; off <<= 1) {
        acc.x += __shfl_xor(acc.x, off, 64);
        acc.y += __shfl_xor(acc.y, off, 64);
        acc.z += __shfl_xor(acc.z, off, 64);
        acc.w += __shfl_xor(acc.w, off, 64);
        den   += __shfl_xor(den,   off, 64);
    }

    if (grp == 0) {
        float inv = (den == 0.0f) ? 1.0f : __frcp_rn(den);
        float4 o = make_float4(acc.x * inv, acc.y * inv, acc.z * inv, acc.w * inv);
        *(float4*)(out + (long long)r * HD + sub * 4) = o;
    }
}

// ---------------- tier-3: fused atomic path ----------------
__global__ void edge_fused_kernel(const float* __restrict__ q,
                                  const float* __restrict__ k,
                                  const float* __restrict__ v,
                                  const float* __restrict__ eigs,
                                  const float* __restrict__ lambda0,
                                  const int* __restrict__ idx,
                                  float* __restrict__ denom,
                                  float* __restrict__ out, int n_edges) {
    long long gid = (long long)blockIdx.x * blockDim.x + threadIdx.x;
    int lane = threadIdx.x & 63;
    int edge = (int)(gid >> 4);
    int sub  = (int)(gid & 15);
    int valid = (edge < n_edges);
    int ec = valid ? edge : (n_edges - 1);
    int i0 = idx[ec];
    int i1 = idx[n_edges + ec];
    const float expL = __expf(lambda0[0]);
    float4 qa = *(const float4*)(q + (long long)i0 * HD + sub * 4);
    float4 kb = *(const float4*)(k + (long long)i1 * HD + sub * 4);
    float c = (qa.x*kb.x + qa.y*kb.y + qa.z*kb.z + qa.w*kb.w) * 0.125f;
    float2 ea = *(const float2*)(eigs + (long long)i0 * ED + sub * 2);
    float2 eb = *(const float2*)(eigs + (long long)i1 * ED + sub * 2);
    c += expL * (ea.x * eb.x + ea.y * eb.y);
    #pragma unroll
    for (int off = 8; off > 0; off >>= 1) c += __shfl_xor(c, off, 64);
    float e = fminf(__expf(c), 5.0f);
    if (valid && sub == 0) atomicAdd(&denom[i0], e);
    #pragma unroll
    for (int j = 0; j < 4; ++j) {
        float ej = __shfl(e,     j * 16, 64);
        int   r  = __shfl(i0,    j * 16, 64);
        int   s  = __shfl(i1,    j * 16, 64);
        int   vj = __shfl(valid, j * 16, 64);
        if (vj) {
            float vv = v[(long long)s * HD + lane];
            atomicAdd(&out[(long long)r * HD + lane], ej * vv);
        }
    }
}

__global__ void normalize_kernel(float* __restrict__ out,
                                 const float* __restrict__ denom, int n_nodes) {
    int t = blockIdx.x * blockDim.x + threadIdx.x;
    int total = n_nodes * (HD / 4);
    if (t >= total) return;
    int row = t >> 4;
    float d = denom[row];
    float inv = (d == 0.0f) ? 1.0f : __frcp_rn(d);
    float4* o4 = (float4*)out;
    float4 x = o4[t];
    x.x *= inv; x.y *= inv; x.z *= inv; x.w *= inv;
    o4[t] = x;
}

extern "C" void kernel_launch(void* const* d_in, const int* in_sizes, int n_in,
                              void* d_out, int out_size, void* d_ws, size_t ws_size,
                              hipStream_t stream) {
    const float* q       = (const float*)d_in[0];
    const float* k       = (const float*)d_in[1];
    const float* v       = (const float*)d_in[2];
    const float* eigs    = (const float*)d_in[3];
    const float* lambda0 = (const float*)d_in[4];
    const int*   idx     = (const int*)d_in[5];   // [2, E], int32

    const int n_edges = in_sizes[5] / 2;
    const int n_nodes = in_sizes[0] / HD;

    const int NP = (n_nodes + RPP - 1) / RPP;
    const int eb = (n_edges + 255) / 256;
    long long rthreads = (long long)n_nodes * 64;
    const int rb = (int)((rthreads + 255) / 256);

    size_t ints1 = ((size_t)n_nodes + (size_t)n_nodes * CAP
                    + (size_t)NP * PCAP + NP + 2) * sizeof(int);
    size_t need1  = ints1 + 8 + (size_t)SPILL_CAP * sizeof(long long);
    size_t h16    = (size_t)n_nodes * (HD + HD + ED) * sizeof(__half);
    size_t need16 = h16 + need1;
    size_t need2  = ((size_t)n_nodes + (size_t)n_nodes * CAP) * sizeof(int);

    if (ws_size >= need16) {
        // -------- tier 1b: fused build + fp16 gather row kernel --------
        char* base = (char*)d_ws;
        __half* k16 = (__half*)base;                    // [N*HD]
        __half* v16 = k16 + (size_t)n_nodes * HD;       // [N*HD]
        __half* e16 = v16 + (size_t)n_nodes * HD;       // [N*ED]
        int* count     = (int*)(e16 + (size_t)n_nodes * ED); // [N]
        int* bucket    = count + n_nodes;               // [N*CAP]
        int* part      = bucket + (size_t)n_nodes * CAP;// [NP*PCAP]
        int* gcur      = part + (size_t)NP * PCAP;      // [NP]
        int* spill_cnt = gcur + NP;                     // [1]
        int* flag      = spill_cnt + 1;                 // [1]
        size_t soff = (size_t)((char*)(flag + 1) - base);
        soff = (soff + 7) & ~(size_t)7;                 // 8B-align spill
        long long* spill = (long long*)(base + soff);   // [SPILL_CAP]

        hipMemsetAsync(gcur, 0, (size_t)(NP + 2) * sizeof(int), stream);

        int chunk = (n_edges + NB1 - 1) / NB1;
        size_t smbytes = (size_t)NP * (2 + D1) * sizeof(int);
        p1_bin_kernel<<<NB1, 256, smbytes, stream>>>(
            idx, n_edges, NP, chunk, part, gcur, spill, spill_cnt, flag,
            k, v, eigs, k16, v16, e16,
            (long long)n_nodes * HD / 4, (long long)n_nodes * ED / 4);
        p2_bucket_kernel<<<2 * NP, 256, 0, stream>>>(part, gcur, count, bucket,
                                                     n_nodes);
        spill_or_zero_kernel<<<(n_nodes + 255) / 256, 256, 0, stream>>>(
            spill, spill_cnt, flag, count, bucket, n_nodes);
        repair_scatter_kernel<<<eb, 256, 0, stream>>>(flag, idx, count, bucket,
                                                      n_edges);
        row16_kernel<<<rb, 256, 0, stream>>>(q, k16, v16, eigs, e16, lambda0,
                                             count, bucket, k, v, idx, n_edges,
                                             (float*)d_out, n_nodes);
    } else if (ws_size >= need1) {
        // -------- tier 1: fused build + fp32 row kernel --------
        char* base = (char*)d_ws;
        int* count     = (int*)base;
        int* bucket    = count + n_nodes;
        int* part      = bucket + (size_t)n_nodes * CAP;
        int* gcur      = part + (size_t)NP * PCAP;
        int* spill_cnt = gcur + NP;
        int* flag      = spill_cnt + 1;
        size_t soff = (size_t)((char*)(flag + 1) - base);
        soff = (soff + 7) & ~(size_t)7;
        long long* spill = (long long*)(base + soff);

        hipMemsetAsync(gcur, 0, (size_t)(NP + 2) * sizeof(int), stream);

        int chunk = (n_edges + NB1 - 1) / NB1;
        size_t smbytes = (size_t)NP * (2 + D1) * sizeof(int);
        p1_bin_kernel<<<NB1, 256, smbytes, stream>>>(
            idx, n_edges, NP, chunk, part, gcur, spill, spill_cnt, flag,
            nullptr, nullptr, nullptr, nullptr, nullptr, nullptr, 0, 0);
        p2_bucket_kernel<<<2 * NP, 256, 0, stream>>>(part, gcur, count, bucket,
                                                     n_nodes);
        spill_or_zero_kernel<<<(n_nodes + 255) / 256, 256, 0, stream>>>(
            spill, spill_cnt, flag, count, bucket, n_nodes);
        repair_scatter_kernel<<<eb, 256, 0, stream>>>(flag, idx, count, bucket,
                                                      n_edges);
        row_kernel<<<rb, 256, 0, stream>>>(q, k, v, eigs, lambda0, count, bucket,
                                           idx, n_edges, (float*)d_out, n_nodes);
    } else if (ws_size >= need2) {
        // -------- tier 2: direct scatter --------
        int* count  = (int*)d_ws;
        int* bucket = count + n_nodes;
        hipMemsetAsync(count, 0, (size_t)n_nodes * sizeof(int), stream);
        bucket_scatter_kernel<<<eb, 256, 0, stream>>>(idx, count, bucket, n_edges);
        row_kernel<<<rb, 256, 0, stream>>>(q, k, v, eigs, lambda0, count, bucket,
                                           idx, n_edges, (float*)d_out, n_nodes);
    } else {
        // -------- tier 3: fused atomic path --------
        float* denom = (float*)d_ws;   // [N]
        hipMemsetAsync(denom, 0, (size_t)n_nodes * sizeof(float), stream);
        hipMemsetAsync(d_out, 0, (size_t)out_size * sizeof(float), stream);
        long long threads = (long long)n_edges * 16;
        int grid = (int)((threads + 255) / 256);
        edge_fused_kernel<<<grid, 256, 0, stream>>>(q, k, v, eigs, lambda0, idx,
                                                    denom, (float*)d_out, n_edges);
        int n4 = n_nodes * (HD / 4);
        normalize_kernel<<<(n4 + 255) / 256, 256, 0, stream>>>((float*)d_out,
                                                               denom, n_nodes);
    }
}

// Round 7
// 259.357 us; speedup vs baseline: 2.2930x; 1.0156x over previous
//
#include <hip/hip_runtime.h>
#include <hip/hip_fp16.h>

// Sparse graph attention (fp32 compute, fp16 gather payloads).
// v8: ZERO-ATOMIC build. Cross-round analysis showed p1 stuck at ~120us in
// every variant (v3 thread-drain, v6 two-phase, v7 4x-occupancy) — the
// invariant was NB1*NP same-address fabric atomicAdds on gcur[391], which
// serialize at the home L2 bank (~1000 RMWs/address). v8 gives each
// (block, partition) a PRIVATE 16-int slice of part (64B line): header m +
// <=15 entries. Drain = aligned full-line stores, no atomics at all.
// D1=15, lambda=4 at NB1=1024 -> P(bin>15)~1.5e-5 -> ~6 spills (spill path
// absorbs). p2 parses slices with 16-lane groups (coalesced 1KB/iter/block),
// LDS bucket fill unchanged. gcur + its memset GONE.
// part grows 6.4->25.6MB: tiers = fp16/nb1024 (84MB) -> fp16/nb512 (71MB,
// lambda=8 -> ~2K spills, still fine) -> fp32/nb1024 -> fp32/nb512 ->
// direct scatter -> fused atomic.
// row16 unchanged (88us, matches gather-transaction model) for attribution.

#define HD 64
#define ED 32
#define CAP 64          // bucket slots per row
#define RPP 256         // rows per partition
#define PSHIFT 8
#define D1 15           // pass-1 LDS bin depth (slice = 16 ints = 64B line)
#define SLICE 16
#define SPILL_CAP 65536

struct h4 { __half2 a, b; };   // 4 halves, 8B

// ---------------- pass 1: partition binning, private-slice drain ---------
__global__ void p1_bin_kernel(const int* __restrict__ idx, int n_edges,
                              int NP, int chunk, int nb, long long pcap,
                              int* __restrict__ part,
                              long long* __restrict__ spill,
                              int* __restrict__ spill_cnt,
                              int* __restrict__ flag,
                              const float* __restrict__ kf,
                              const float* __restrict__ vf,
                              const float* __restrict__ ef,
                              __half* __restrict__ k16,
                              __half* __restrict__ v16,
                              __half* __restrict__ e16,
                              long long nk4, long long ne4) {
    extern __shared__ int sm[];          // [NP] cnt, [NP*D1] bins
    int* cnt  = sm;
    int* bins = sm + NP;
    int tid = threadIdx.x;

    for (int i = tid; i < NP; i += 256) cnt[i] = 0;
    __syncthreads();

    int e0 = blockIdx.x * chunk;
    int n  = n_edges - e0; if (n > chunk) n = chunk; if (n < 0) n = 0;

    for (int i = tid; i < n; i += 256) {
        int e = e0 + i;
        int r = idx[e];
        int c = idx[n_edges + e];
        int p = r >> PSHIFT;
        int w = ((r & (RPP - 1)) << 17) | c;
        int pos = atomicAdd(&cnt[p], 1);         // LDS atomic only
        if (pos < D1) {
            bins[p * D1 + pos] = w;
        } else {                                 // statistical overflow (~6)
            int s = atomicAdd(spill_cnt, 1);
            if (s < SPILL_CAP) spill[s] = ((long long)r << 32) | (unsigned)c;
            else *flag = 1;
        }
    }
    __syncthreads();

    // drain: 16-lane group per slice; one aligned 64B line store per slice.
    // NO atomics, no inter-block coordination.
    int g16 = tid >> 4;      // group 0..15
    int sl  = tid & 15;      // slot in slice
    for (int p = g16; p < NP; p += 16) {
        int m = cnt[p]; if (m > D1) m = D1;
        long long base = (long long)p * pcap + (long long)blockIdx.x * SLICE;
        int val = (sl == 0) ? m
                : (sl <= m) ? bins[p * D1 + sl - 1] : 0;
        part[base + sl] = val;   // full 16-lane line write
    }

    // fused fp16 conversion tail (skipped when k16==nullptr).
    if (k16 != nullptr) {
        long long gt = (long long)blockIdx.x * 256 + tid;
        long long gs = (long long)gridDim.x * 256;
        for (long long t = gt; t < nk4; t += gs) {
            float4 f = ((const float4*)kf)[t];
            h4 h;
            h.a = __floats2half2_rn(f.x, f.y);
            h.b = __floats2half2_rn(f.z, f.w);
            ((h4*)k16)[t] = h;
        }
        for (long long t = gt; t < nk4; t += gs) {
            float4 f = ((const float4*)vf)[t];
            h4 h;
            h.a = __floats2half2_rn(f.x, f.y);
            h.b = __floats2half2_rn(f.z, f.w);
            ((h4*)v16)[t] = h;
        }
        for (long long t = gt; t < ne4; t += gs) {
            float4 f = ((const float4*)ef)[t];
            h4 h;
            h.a = __floats2half2_rn(f.x, f.y);
            h.b = __floats2half2_rn(f.z, f.w);
            ((h4*)e16)[t] = h;
        }
    }
}

// ---------------- pass 2: slice parse + LDS-staged bucket fill -----------
__global__ void p2_bucket_kernel(const int* __restrict__ part,
                                 int* __restrict__ count,
                                 int* __restrict__ bucket, int n_nodes,
                                 int nb, long long pcap) {
    __shared__ int cnt2[RPP / 2];         // 128 counters
    __shared__ int win[(RPP / 2) * CAP];  // 32KB staged window
    int tid = threadIdx.x;
    if (tid < RPP / 2) cnt2[tid] = 0;
    __syncthreads();

    int p    = blockIdx.x >> 1;
    int half = blockIdx.x & 1;
    int g  = tid >> 4;       // 16 groups
    int sl = tid & 15;
    const int* prow = part + (long long)p * pcap;

    for (int b = g; b < nb; b += 16) {
        int val = prow[b * SLICE + sl];        // block reads 1KB contiguous
        int m = __shfl(val, 0, 16);            // broadcast header in group
        if (m > D1) m = D1;
        if (sl >= 1 && sl <= m) {
            int rl = val >> 17;                // 0..255 within partition
            if ((rl >> 7) == half) {
                int rh = rl & 127;
                int c  = val & 0x1FFFF;
                int pos = atomicAdd(&cnt2[rh], 1);   // LDS atomic
                if (pos < CAP) win[(rh << 6) + pos] = c;
            }
        }
    }
    __syncthreads();

    int r0 = (p << PSHIFT) + (half << 7);
    int rows = n_nodes - r0;
    if (rows > RPP / 2) rows = RPP / 2;
    if (rows > 0) {
        int nint4 = rows * (CAP / 4);
        int4* dst = (int4*)(bucket + (long long)r0 * CAP);
        const int4* src = (const int4*)win;
        for (int i = tid; i < nint4; i += 256) dst[i] = src[i];
        if (tid < rows) count[r0 + tid] = cnt2[tid];
    }
}

// ---------------- spill drain OR count-zero (flag branch) ----------------
__global__ void spill_or_zero_kernel(const long long* __restrict__ spill,
                                     const int* __restrict__ spill_cnt,
                                     const int* __restrict__ flag,
                                     int* __restrict__ count,
                                     int* __restrict__ bucket, int n_nodes) {
    int stride = gridDim.x * blockDim.x;
    int t0 = blockIdx.x * blockDim.x + threadIdx.x;
    if (*flag) {
        for (int t = t0; t < n_nodes; t += stride) count[t] = 0;
        return;
    }
    int ns = *spill_cnt; if (ns > SPILL_CAP) ns = SPILL_CAP;
    for (int t = t0; t < ns; t += stride) {
        long long wc = spill[t];
        int r = (int)(wc >> 32);
        int c = (int)(wc & 0xFFFFFFFFLL);
        int pos = atomicAdd(&count[r], 1);
        if (pos < CAP) bucket[(long long)r * CAP + pos] = c;
    }
}

__global__ void repair_scatter_kernel(const int* __restrict__ flag,
                                      const int* __restrict__ idx,
                                      int* __restrict__ count,
                                      int* __restrict__ bucket, int n_edges) {
    if (*flag == 0) return;
    int t = blockIdx.x * blockDim.x + threadIdx.x;
    if (t < n_edges) {
        int r = idx[t];
        int c = idx[n_edges + t];
        int p = atomicAdd(&count[r], 1);
        if (p < CAP) bucket[(long long)r * CAP + p] = c;
    }
}

// ---------------- fallback build: direct scatter ----------------
__global__ void bucket_scatter_kernel(const int* __restrict__ idx,
                                      int* __restrict__ count,
                                      int* __restrict__ bucket, int n_edges) {
    int t = blockIdx.x * blockDim.x + threadIdx.x;
    if (t < n_edges) {
        int r = idx[t];
        int c = idx[n_edges + t];
        int p = atomicAdd(&count[r], 1);
        if (p < CAP) bucket[(long long)r * CAP + p] = c;
    }
}

// ---------------- row kernel, fp16 gathers (unchanged) ----------------
__global__ void row16_kernel(const float* __restrict__ q,
                             const __half* __restrict__ k16,
                             const __half* __restrict__ v16,
                             const float* __restrict__ eigs,
                             const __half* __restrict__ e16,
                             const float* __restrict__ lambda0,
                             const int* __restrict__ counts,
                             const int* __restrict__ col,
                             const float* __restrict__ kf,
                             const float* __restrict__ vf,
                             const int* __restrict__ idx, int n_edges,
                             float* __restrict__ out, int n_nodes) {
    long long tid = (long long)blockIdx.x * blockDim.x + threadIdx.x;
    int r = (int)(tid >> 6);
    if (r >= n_nodes) return;
    int lane = threadIdx.x & 63;
    int sub = lane & 15;
    int grp = lane >> 4;

    int deg = counts[r];
    const float expL = __expf(lambda0[0]);

    if (deg > CAP) {
        float qs = q[(long long)r * HD + lane] * 0.125f;
        float gs = (lane < ED) ? eigs[(long long)r * ED + lane] * expL : 0.f;
        float accs = 0.f, den = 0.f;
        for (int base = 0; base < n_edges; base += 64) {
            int e = base + lane;
            int rr = (e < n_edges) ? idx[e] : -1;
            int cc = (e < n_edges) ? idx[n_edges + e] : 0;
            unsigned long long mm = __ballot(rr == r);
            while (mm) {
                int b = __ffsll(mm) - 1;
                mm &= mm - 1;
                int c = __shfl(cc, b, 64);
                float kb = kf[(long long)c * HD + lane];
                float gb = (lane < ED) ? eigs[(long long)c * ED + lane] : 0.f;
                float s = qs * kb + gs * gb;
                #pragma unroll
                for (int off = 32; off > 0; off >>= 1) s += __shfl_xor(s, off, 64);
                float e1 = fminf(__expf(s), 5.0f);
                den += e1;
                accs += e1 * vf[(long long)c * HD + lane];
            }
        }
        float inv = (den == 0.f) ? 1.f : __frcp_rn(den);
        out[(long long)r * HD + lane] = accs * inv;
        return;
    }

    long long start = (long long)r * CAP;

    float4 qa = *(const float4*)(q    + (long long)r * HD + sub * 4);
    float2 ga = *(const float2*)(eigs + (long long)r * ED + sub * 2);
    qa.x *= 0.125f; qa.y *= 0.125f; qa.z *= 0.125f; qa.w *= 0.125f;
    ga.x *= expL;   ga.y *= expL;

    float4 acc = make_float4(0.f, 0.f, 0.f, 0.f);
    float den = 0.f;

    for (int base = 0; base < deg; base += 64) {
        int m = deg - base; if (m > 64) m = 64;
        int cl = (lane < m) ? col[start + base + lane] : 0;
        for (int j = 0; j < m; j += 16) {
            int c1 = __shfl(cl, j + grp,      64);
            int c2 = __shfl(cl, j + 4 + grp,  64);
            int c3 = __shfl(cl, j + 8 + grp,  64);
            int c4 = __shfl(cl, j + 12 + grp, 64);
            h4 kb1 = *(const h4*)(k16 + (long long)c1 * HD + sub * 4);
            __half2 gh1 = *(const __half2*)(e16 + (long long)c1 * ED + sub * 2);
            h4 vv1 = *(const h4*)(v16 + (long long)c1 * HD + sub * 4);
            h4 kb2 = *(const h4*)(k16 + (long long)c2 * HD + sub * 4);
            __half2 gh2 = *(const __half2*)(e16 + (long long)c2 * ED + sub * 2);
            h4 vv2 = *(const h4*)(v16 + (long long)c2 * HD + sub * 4);
            h4 kb3 = *(const h4*)(k16 + (long long)c3 * HD + sub * 4);
            __half2 gh3 = *(const __half2*)(e16 + (long long)c3 * ED + sub * 2);
            h4 vv3 = *(const h4*)(v16 + (long long)c3 * HD + sub * 4);
            h4 kb4 = *(const h4*)(k16 + (long long)c4 * HD + sub * 4);
            __half2 gh4 = *(const __half2*)(e16 + (long long)c4 * ED + sub * 2);
            h4 vv4 = *(const h4*)(v16 + (long long)c4 * HD + sub * 4);

            float s1 = qa.x*__low2float(kb1.a) + qa.y*__high2float(kb1.a)
                     + qa.z*__low2float(kb1.b) + qa.w*__high2float(kb1.b)
                     + ga.x*__low2float(gh1)   + ga.y*__high2float(gh1);
            float s2 = qa.x*__low2float(kb2.a) + qa.y*__high2float(kb2.a)
                     + qa.z*__low2float(kb2.b) + qa.w*__high2float(kb2.b)
                     + ga.x*__low2float(gh2)   + ga.y*__high2float(gh2);
            float s3 = qa.x*__low2float(kb3.a) + qa.y*__high2float(kb3.a)
                     + qa.z*__low2float(kb3.b) + qa.w*__high2float(kb3.b)
                     + ga.x*__low2float(gh3)   + ga.y*__high2float(gh3);
            float s4 = qa.x*__low2float(kb4.a) + qa.y*__high2float(kb4.a)
                     + qa.z*__low2float(kb4.b) + qa.w*__high2float(kb4.b)
                     + ga.x*__low2float(gh4)   + ga.y*__high2float(gh4);
            #pragma unroll
            for (int off = 8; off > 0; off >>= 1) {
                s1 += __shfl_xor(s1, off, 64);
                s2 += __shfl_xor(s2, off, 64);
                s3 += __shfl_xor(s3, off, 64);
                s4 += __shfl_xor(s4, off, 64);
            }
            float e1 = fminf(__expf(s1), 5.0f);
            float e2 = fminf(__expf(s2), 5.0f);
            float e3 = fminf(__expf(s3), 5.0f);
            float e4 = fminf(__expf(s4), 5.0f);

            if (j + grp < m) {
                den += e1;
                acc.x += e1 * __low2float(vv1.a); acc.y += e1 * __high2float(vv1.a);
                acc.z += e1 * __low2float(vv1.b); acc.w += e1 * __high2float(vv1.b);
            }
            if (j + 4 + grp < m) {
                den += e2;
                acc.x += e2 * __low2float(vv2.a); acc.y += e2 * __high2float(vv2.a);
                acc.z += e2 * __low2float(vv2.b); acc.w += e2 * __high2float(vv2.b);
            }
            if (j + 8 + grp < m) {
                den += e3;
                acc.x += e3 * __low2float(vv3.a); acc.y += e3 * __high2float(vv3.a);
                acc.z += e3 * __low2float(vv3.b); acc.w += e3 * __high2float(vv3.b);
            }
            if (j + 12 + grp < m) {
                den += e4;
                acc.x += e4 * __low2float(vv4.a); acc.y += e4 * __high2float(vv4.a);
                acc.z += e4 * __low2float(vv4.b); acc.w += e4 * __high2float(vv4.b);
            }
        }
    }

    #pragma unroll
    for (int off = 16; off < 64; off <<= 1) {
        acc.x += __shfl_xor(acc.x, off, 64);
        acc.y += __shfl_xor(acc.y, off, 64);
        acc.z += __shfl_xor(acc.z, off, 64);
        acc.w += __shfl_xor(acc.w, off, 64);
        den   += __shfl_xor(den,   off, 64);
    }

    if (grp == 0) {
        float inv = (den == 0.0f) ? 1.0f : __frcp_rn(den);
        float4 o = make_float4(acc.x * inv, acc.y * inv, acc.z * inv, acc.w * inv);
        *(float4*)(out + (long long)r * HD + sub * 4) = o;
    }
}

// ---------------- row kernel, fp32 (fallback tiers) ----------------
__global__ void row_kernel(const float* __restrict__ q, const float* __restrict__ k,
                           const float* __restrict__ v, const float* __restrict__ eigs,
                           const float* __restrict__ lambda0,
                           const int* __restrict__ counts,
                           const int* __restrict__ col,
                           const int* __restrict__ idx, int n_edges,
                           float* __restrict__ out, int n_nodes) {
    long long tid = (long long)blockIdx.x * blockDim.x + threadIdx.x;
    int r = (int)(tid >> 6);
    if (r >= n_nodes) return;
    int lane = threadIdx.x & 63;
    int sub = lane & 15;
    int grp = lane >> 4;

    int deg = counts[r];
    const float expL = __expf(lambda0[0]);

    if (deg > CAP) {
        float qs = q[(long long)r * HD + lane] * 0.125f;
        float gs = (lane < ED) ? eigs[(long long)r * ED + lane] * expL : 0.f;
        float accs = 0.f, den = 0.f;
        for (int base = 0; base < n_edges; base += 64) {
            int e = base + lane;
            int rr = (e < n_edges) ? idx[e] : -1;
            int cc = (e < n_edges) ? idx[n_edges + e] : 0;
            unsigned long long mm = __ballot(rr == r);
            while (mm) {
                int b = __ffsll(mm) - 1;
                mm &= mm - 1;
                int c = __shfl(cc, b, 64);
                float kb = k[(long long)c * HD + lane];
                float gb = (lane < ED) ? eigs[(long long)c * ED + lane] : 0.f;
                float s = qs * kb + gs * gb;
                #pragma unroll
                for (int off = 32; off > 0; off >>= 1) s += __shfl_xor(s, off, 64);
                float e1 = fminf(__expf(s), 5.0f);
                den += e1;
                accs += e1 * v[(long long)c * HD + lane];
            }
        }
        float inv = (den == 0.f) ? 1.f : __frcp_rn(den);
        out[(long long)r * HD + lane] = accs * inv;
        return;
    }

    long long start = (long long)r * CAP;

    float4 qa = *(const float4*)(q    + (long long)r * HD + sub * 4);
    float2 ga = *(const float2*)(eigs + (long long)r * ED + sub * 2);
    qa.x *= 0.125f; qa.y *= 0.125f; qa.z *= 0.125f; qa.w *= 0.125f;
    ga.x *= expL;   ga.y *= expL;

    float4 acc = make_float4(0.f, 0.f, 0.f, 0.f);
    float den = 0.f;

    for (int base = 0; base < deg; base += 64) {
        int m = deg - base; if (m > 64) m = 64;
        int cl = (lane < m) ? col[start + base + lane] : 0;
        for (int j = 0; j < m; j += 8) {
            int c1 = __shfl(cl, j + grp,     64);
            int c2 = __shfl(cl, j + 4 + grp, 64);
            float4 kb1 = *(const float4*)(k    + (long long)c1 * HD + sub * 4);
            float2 gb1 = *(const float2*)(eigs + (long long)c1 * ED + sub * 2);
            float4 vv1 = *(const float4*)(v    + (long long)c1 * HD + sub * 4);
            float4 kb2 = *(const float4*)(k    + (long long)c2 * HD + sub * 4);
            float2 gb2 = *(const float2*)(eigs + (long long)c2 * ED + sub * 2);
            float4 vv2 = *(const float4*)(v    + (long long)c2 * HD + sub * 4);

            float s1 = qa.x*kb1.x + qa.y*kb1.y + qa.z*kb1.z + qa.w*kb1.w
                     + ga.x*gb1.x + ga.y*gb1.y;
            float s2 = qa.x*kb2.x + qa.y*kb2.y + qa.z*kb2.z + qa.w*kb2.w
                     + ga.x*gb2.x + ga.y*gb2.y;
            #pragma unroll
            for (int off = 8; off > 0; off >>= 1) {
                s1 += __shfl_xor(s1, off, 64);
                s2 += __shfl_xor(s2, off, 64);
            }
            float e1 = fminf(__expf(s1), 5.0f);
            float e2 = fminf(__expf(s2), 5.0f);

            if (j + grp < m) {
                den += e1;
                acc.x += e1 * vv1.x; acc.y += e1 * vv1.y;
                acc.z += e1 * vv1.z; acc.w += e1 * vv1.w;
            }
            if (j + 4 + grp < m) {
                den += e2;
                acc.x += e2 * vv2.x; acc.y += e2 * vv2.y;
                acc.z += e2 * vv2.z; acc.w += e2 * vv2.w;
            }
        }
    }

    #pragma unroll
    for (int off = 16; off < 64; off <<= 1) {
        acc.x += __shfl_xor(acc.x, off, 64);
        acc.y += __shfl_xor(acc.y, off, 64);
        acc.z += __shfl_xor(acc.z, off, 64);
        acc.w += __shfl_xor(acc.w, off, 64);
        den   += __shfl_xor(den,   off, 64);
    }

    if (grp == 0) {
        float inv = (den == 0.0f) ? 1.0f : __frcp_rn(den);
        float4 o = make_float4(acc.x * inv, acc.y * inv, acc.z * inv, acc.w * inv);
        *(float4*)(out + (long long)r * HD + sub * 4) = o;
    }
}

// ---------------- tier-3: fused atomic path ----------------
__global__ void edge_fused_kernel(const float* __restrict__ q,
                                  const float* __restrict__ k,
                                  const float* __restrict__ v,
                                  const float* __restrict__ eigs,
                                  const float* __restrict__ lambda0,
                                  const int* __restrict__ idx,
                                  float* __restrict__ denom,
                                  float* __restrict__ out, int n_edges) {
    long long gid = (long long)blockIdx.x * blockDim.x + threadIdx.x;
    int lane = threadIdx.x & 63;
    int edge = (int)(gid >> 4);
    int sub  = (int)(gid & 15);
    int valid = (edge < n_edges);
    int ec = valid ? edge : (n_edges - 1);
    int i0 = idx[ec];
    int i1 = idx[n_edges + ec];
    const float expL = __expf(lambda0[0]);
    float4 qa = *(const float4*)(q + (long long)i0 * HD + sub * 4);
    float4 kb = *(const float4*)(k + (long long)i1 * HD + sub * 4);
    float c = (qa.x*kb.x + qa.y*kb.y + qa.z*kb.z + qa.w*kb.w) * 0.125f;
    float2 ea = *(const float2*)(eigs + (long long)i0 * ED + sub * 2);
    float2 eb = *(const float2*)(eigs + (long long)i1 * ED + sub * 2);
    c += expL * (ea.x * eb.x + ea.y * eb.y);
    #pragma unroll
    for (int off = 8; off > 0; off >>= 1) c += __shfl_xor(c, off, 64);
    float e = fminf(__expf(c), 5.0f);
    if (valid && sub == 0) atomicAdd(&denom[i0], e);
    #pragma unroll
    for (int j = 0; j < 4; ++j) {
        float ej = __shfl(e,     j * 16, 64);
        int   r  = __shfl(i0,    j * 16, 64);
        int   s  = __shfl(i1,    j * 16, 64);
        int   vj = __shfl(valid, j * 16, 64);
        if (vj) {
            float vv = v[(long long)s * HD + lane];
            atomicAdd(&out[(long long)r * HD + lane], ej * vv);
        }
    }
}

__global__ void normalize_kernel(float* __restrict__ out,
                                 const float* __restrict__ denom, int n_nodes) {
    int t = blockIdx.x * blockDim.x + threadIdx.x;
    int total = n_nodes * (HD / 4);
    if (t >= total) return;
    int row = t >> 4;
    float d = denom[row];
    float inv = (d == 0.0f) ? 1.0f : __frcp_rn(d);
    float4* o4 = (float4*)out;
    float4 x = o4[t];
    x.x *= inv; x.y *= inv; x.z *= inv; x.w *= inv;
    o4[t] = x;
}

extern "C" void kernel_launch(void* const* d_in, const int* in_sizes, int n_in,
                              void* d_out, int out_size, void* d_ws, size_t ws_size,
                              hipStream_t stream) {
    const float* q       = (const float*)d_in[0];
    const float* k       = (const float*)d_in[1];
    const float* v       = (const float*)d_in[2];
    const float* eigs    = (const float*)d_in[3];
    const float* lambda0 = (const float*)d_in[4];
    const int*   idx     = (const int*)d_in[5];   // [2, E], int32

    const int n_edges = in_sizes[5] / 2;
    const int n_nodes = in_sizes[0] / HD;

    const int NP = (n_nodes + RPP - 1) / RPP;
    const int eb = (n_edges + 255) / 256;
    long long rthreads = (long long)n_nodes * 64;
    const int rb = (int)((rthreads + 255) / 256);

    // geometry guards for the binned path
    size_t smbytes = (size_t)NP * (1 + D1) * sizeof(int);
    bool geom_ok = (smbytes <= 60 * 1024) && (n_nodes <= 0x1FFFF);

    size_t fixed = (size_t)n_nodes * sizeof(int)             // count
                 + (size_t)n_nodes * CAP * sizeof(int);      // bucket
    size_t sp = 8 + (size_t)SPILL_CAP * sizeof(long long);   // cnt/flag + spill
    size_t h16 = (size_t)n_nodes * (HD + HD + ED) * sizeof(__half);

    auto part_bytes = [&](int nb) {
        return (size_t)NP * (size_t)nb * SLICE * sizeof(int);
    };
    size_t n16_1024 = h16 + fixed + part_bytes(1024) + sp;
    size_t n16_512  = h16 + fixed + part_bytes(512)  + sp;
    size_t n32_1024 = fixed + part_bytes(1024) + sp;
    size_t n32_512  = fixed + part_bytes(512)  + sp;
    size_t need2    = fixed;

    bool use16 = false;
    int nb = 0;
    if (geom_ok && ws_size >= n16_1024)      { use16 = true;  nb = 1024; }
    else if (geom_ok && ws_size >= n16_512)  { use16 = true;  nb = 512;  }
    else if (geom_ok && ws_size >= n32_1024) { use16 = false; nb = 1024; }
    else if (geom_ok && ws_size >= n32_512)  { use16 = false; nb = 512;  }

    if (nb > 0) {
        // -------- tier 1: zero-atomic private-slice build --------
        char* base = (char*)d_ws;
        __half* k16 = nullptr; __half* v16 = nullptr; __half* e16 = nullptr;
        char* ip = base;
        if (use16) {
            k16 = (__half*)base;
            v16 = k16 + (size_t)n_nodes * HD;
            e16 = v16 + (size_t)n_nodes * HD;
            ip = (char*)(e16 + (size_t)n_nodes * ED);
        }
        int* count  = (int*)ip;                          // [N]
        int* bucket = count + n_nodes;                   // [N*CAP]
        int* part   = bucket + (size_t)n_nodes * CAP;    // [NP*nb*SLICE]
        long long pcap = (long long)nb * SLICE;
        int* spill_cnt = part + (size_t)NP * pcap;       // [1]
        int* flag      = spill_cnt + 1;                  // [1]
        size_t soff = (size_t)((char*)(flag + 1) - base);
        soff = (soff + 7) & ~(size_t)7;
        long long* spill = (long long*)(base + soff);    // [SPILL_CAP]

        hipMemsetAsync(spill_cnt, 0, 2 * sizeof(int), stream);

        int chunk = (n_edges + nb - 1) / nb;
        p1_bin_kernel<<<nb, 256, smbytes, stream>>>(
            idx, n_edges, NP, chunk, nb, pcap, part, spill, spill_cnt, flag,
            k, v, eigs, k16, v16, e16,
            use16 ? (long long)n_nodes * HD / 4 : 0,
            use16 ? (long long)n_nodes * ED / 4 : 0);
        p2_bucket_kernel<<<2 * NP, 256, 0, stream>>>(part, count, bucket,
                                                     n_nodes, nb, pcap);
        spill_or_zero_kernel<<<(n_nodes + 255) / 256, 256, 0, stream>>>(
            spill, spill_cnt, flag, count, bucket, n_nodes);
        repair_scatter_kernel<<<eb, 256, 0, stream>>>(flag, idx, count, bucket,
                                                      n_edges);
        if (use16) {
            row16_kernel<<<rb, 256, 0, stream>>>(q, k16, v16, eigs, e16, lambda0,
                                                 count, bucket, k, v, idx,
                                                 n_edges, (float*)d_out, n_nodes);
        } else {
            row_kernel<<<rb, 256, 0, stream>>>(q, k, v, eigs, lambda0, count,
                                               bucket, idx, n_edges,
                                               (float*)d_out, n_nodes);
        }
    } else if (ws_size >= need2) {
        // -------- tier 2: direct scatter --------
        int* count  = (int*)d_ws;
        int* bucket = count + n_nodes;
        hipMemsetAsync(count, 0, (size_t)n_nodes * sizeof(int), stream);
        bucket_scatter_kernel<<<eb, 256, 0, stream>>>(idx, count, bucket, n_edges);
        row_kernel<<<rb, 256, 0, stream>>>(q, k, v, eigs, lambda0, count, bucket,
                                           idx, n_edges, (float*)d_out, n_nodes);
    } else {
        // -------- tier 3: fused atomic path --------
        float* denom = (float*)d_ws;   // [N]
        hipMemsetAsync(denom, 0, (size_t)n_nodes * sizeof(float), stream);
        hipMemsetAsync(d_out, 0, (size_t)out_size * sizeof(float), stream);
        long long threads = (long long)n_edges * 16;
        int grid = (int)((threads + 255) / 256);
        edge_fused_kernel<<<grid, 256, 0, stream>>>(q, k, v, eigs, lambda0, idx,
                                                    denom, (float*)d_out, n_edges);
        int n4 = n_nodes * (HD / 4);
        normalize_kernel<<<(n4 + 255) / 256, 256, 0, stream>>>((float*)d_out,
                                                               denom, n_nodes);
    }
}